// Round 9
// baseline (395.128 us; speedup 1.0000x reference)
//
#include <hip/hip_runtime.h>
#include <hip/hip_bf16.h>

#define B_ 16
#define N_ 1024
#define C_ 256
#define R_ 8
#define E_ 262144
#define NS_ 32
#define BN_ (B_*N_)
#define BNC_ (BN_*C_)

typedef __hip_bfloat16 bf16;
typedef __attribute__((ext_vector_type(4))) float f32x4;
typedef __attribute__((ext_vector_type(8))) short bf16x8;

__device__ __forceinline__ float b2f(bf16 x) { return __bfloat162float(x); }
__device__ __forceinline__ bf16  f2b(float x) { return __float2bfloat16(x); }
__device__ __forceinline__ unsigned short f2bu(float x) { bf16 b = f2b(x); return *(unsigned short*)&b; }
__device__ __forceinline__ float us2f(unsigned short u) { return __uint_as_float((unsigned)u << 16); }

// async global->LDS, 16B per lane (wave-uniform LDS base + lane*16 implicit)
__device__ __forceinline__ void gload16(const void* g, void* l) {
    auto gp = (const __attribute__((address_space(1))) void*)(unsigned long long)g;
    auto lp = (__attribute__((address_space(3))) void*)(unsigned)(unsigned long long)l;
    __builtin_amdgcn_global_load_lds(gp, lp, 16, 0, 0);
}

// ---------------- bf16 MFMA GEMM (128x128 tile): C = act(A @ B^T + bias) ----------------
// Depth-2 pipeline, counted vmcnt(4); XOR slot swizzle both sides (rule #21).
template<int ACT>
__global__ __launch_bounds__(256) void gemm_bf16(
    const bf16* __restrict__ A, int lda, long long sA,
    const bf16* __restrict__ Bm, int ldb, long long sB,
    bf16* __restrict__ Cc, int ldc, long long sC,
    const float* __restrict__ bias, const float* __restrict__ bias2,
    const float* __restrict__ bias3, int K)
{
    __shared__ short sbuf[16384];        // 32 KB
    const int tid = threadIdx.x;
    const int lane = tid & 63, w = tid >> 6;
    const int wr = w >> 1, wc = w & 1;
    const int bm = blockIdx.y * 128, bn = blockIdx.x * 128;
    const bf16* Ab = A + (size_t)blockIdx.z * sA;
    const bf16* Bb = Bm + (size_t)blockIdx.z * sB;
    bf16* Cb = Cc + (size_t)blockIdx.z * sC;

    const int rg = lane >> 2;
    const int kswz = ((lane & 3) ^ ((rg >> 1) & 3)) * 8;

    f32x4 acc[4][4];
    const f32x4 zz = {0.f, 0.f, 0.f, 0.f};
    #pragma unroll
    for (int i = 0; i < 4; ++i)
        #pragma unroll
        for (int j = 0; j < 4; ++j) acc[i][j] = zz;

    const int fr = lane & 15;
    const int fm = lane >> 4;
    const int fslot = (fm ^ ((fr >> 1) & 3)) * 8;

    const int NI = K >> 5;

#define STAGE_AB(bi, kk) do {                                                          \
    _Pragma("unroll")                                                                  \
    for (int t_ = 0; t_ < 2; ++t_) {                                                   \
        gload16(Ab + (size_t)(bm + t_*64 + w*16 + rg) * lda + (kk) + kswz,             \
                sbuf + (bi)*4096 + t_*2048 + w*512);                                   \
        gload16(Bb + (size_t)(bn + t_*64 + w*16 + rg) * ldb + (kk) + kswz,             \
                sbuf + 8192 + (bi)*4096 + t_*2048 + w*512);                            \
    } } while (0)

    STAGE_AB(0, 0);
    if (NI > 1) STAGE_AB(1, 32);

    for (int i = 0; i < NI; ++i) {
        const int cur = i & 1;
        if (i + 1 < NI) asm volatile("s_waitcnt vmcnt(4)" ::: "memory");
        else            asm volatile("s_waitcnt vmcnt(0)" ::: "memory");
        __builtin_amdgcn_s_barrier();
        __builtin_amdgcn_sched_barrier(0);

        bf16x8 af[4], bfr[4];
        const short* Ac = sbuf + cur * 4096;
        const short* Bc = sbuf + 8192 + cur * 4096;
        #pragma unroll
        for (int ii = 0; ii < 4; ++ii)
            af[ii] = *(const bf16x8*)&Ac[(wr*64 + ii*16 + fr)*32 + fslot];
        #pragma unroll
        for (int jj = 0; jj < 4; ++jj)
            bfr[jj] = *(const bf16x8*)&Bc[(wc*64 + jj*16 + fr)*32 + fslot];

        asm volatile("s_waitcnt lgkmcnt(0)" ::: "memory");
        __builtin_amdgcn_s_barrier();
        __builtin_amdgcn_sched_barrier(0);
        if (i + 2 < NI) STAGE_AB(cur, (i + 2) * 32);

        #pragma unroll
        for (int ii = 0; ii < 4; ++ii)
            #pragma unroll
            for (int jj = 0; jj < 4; ++jj)
                acc[ii][jj] = __builtin_amdgcn_mfma_f32_16x16x32_bf16(af[ii], bfr[jj], acc[ii][jj], 0, 0, 0);
    }
#undef STAGE_AB

    __syncthreads();
    const int er = (lane >> 4) * 4, ec = lane & 15;
    #pragma unroll
    for (int half = 0; half < 2; ++half) {
        if (wr == half) {
            #pragma unroll
            for (int j = 0; j < 4; ++j) {
                const int col = bn + wc*64 + j*16 + ec;
                float bvv = 0.0f;
                if (bias) {
                    const int seg = col >> 8;
                    const float* bp = (seg == 0) ? bias : (seg == 1 ? bias2 : bias3);
                    bvv = bp[col & 255];
                }
                #pragma unroll
                for (int i = 0; i < 4; ++i) {
                    #pragma unroll
                    for (int p = 0; p < 4; ++p) {
                        float val = acc[i][j][p] + bvv;
                        if (ACT == 1) val = fmaxf(val, 0.0f);
                        if (ACT == 2) val = 1.0f / (1.0f + __expf(-val));
                        *(bf16*)&sbuf[(i*16 + er + p)*136 + wc*64 + j*16 + ec] = f2b(val);
                    }
                }
            }
        }
        __syncthreads();
        #pragma unroll
        for (int it = 0; it < 4; ++it) {
            const int ch = tid + it*256;
            const int row = ch >> 4, cp = (ch & 15) * 8;
            *(bf16x8*)&Cb[(size_t)(bm + half*64 + row) * ldc + bn + cp] =
                *(const bf16x8*)&sbuf[row*136 + cp];
        }
        __syncthreads();
    }
}

// ---------------- bf16 MFMA GEMM (64x64 tile, 4-wave 32x32 quadrants) ----------------
template<int ACT>
__global__ __launch_bounds__(256) void gemm64_bf16(
    const bf16* __restrict__ A, int lda, long long sA,
    const bf16* __restrict__ Bm, int ldb, long long sB,
    bf16* __restrict__ Cc, int ldc, long long sC,
    const float* __restrict__ bias, int K)
{
    __shared__ short sbuf[8192];
    const int tid = threadIdx.x;
    const int lane = tid & 63, w = tid >> 6;
    const int wr = w >> 1, wc = w & 1;
    const int bm = blockIdx.y * 64, bn = blockIdx.x * 64;
    const bf16* Ab = A + (size_t)blockIdx.z * sA;
    const bf16* Bb = Bm + (size_t)blockIdx.z * sB;
    bf16* Cb = Cc + (size_t)blockIdx.z * sC;

    const int rg = lane >> 2;
    const int kswz = ((lane & 3) ^ ((rg >> 1) & 3)) * 8;

    f32x4 acc[2][2];
    const f32x4 zz = {0.f, 0.f, 0.f, 0.f};
    #pragma unroll
    for (int i = 0; i < 2; ++i)
        #pragma unroll
        for (int j = 0; j < 2; ++j) acc[i][j] = zz;

    const int fr = lane & 15;
    const int fm = lane >> 4;
    const int fslot = (fm ^ ((fr >> 1) & 3)) * 8;

    const int NI = K >> 5;

#define STAGE64(bi, kk) do {                                                           \
    gload16(Ab + (size_t)(bm + w*16 + rg) * lda + (kk) + kswz,                         \
            sbuf + (bi)*2048 + w*512);                                                 \
    gload16(Bb + (size_t)(bn + w*16 + rg) * ldb + (kk) + kswz,                         \
            sbuf + 4096 + (bi)*2048 + w*512);                                          \
    } while (0)

    STAGE64(0, 0);
    if (NI > 1) STAGE64(1, 32);

    for (int i = 0; i < NI; ++i) {
        const int cur = i & 1;
        if (i + 1 < NI) asm volatile("s_waitcnt vmcnt(2)" ::: "memory");
        else            asm volatile("s_waitcnt vmcnt(0)" ::: "memory");
        __builtin_amdgcn_s_barrier();
        __builtin_amdgcn_sched_barrier(0);

        bf16x8 af[2], bfr[2];
        const short* Ac = sbuf + cur * 2048;
        const short* Bc = sbuf + 4096 + cur * 2048;
        #pragma unroll
        for (int ii = 0; ii < 2; ++ii)
            af[ii] = *(const bf16x8*)&Ac[(wr*32 + ii*16 + fr)*32 + fslot];
        #pragma unroll
        for (int jj = 0; jj < 2; ++jj)
            bfr[jj] = *(const bf16x8*)&Bc[(wc*32 + jj*16 + fr)*32 + fslot];

        asm volatile("s_waitcnt lgkmcnt(0)" ::: "memory");
        __builtin_amdgcn_s_barrier();
        __builtin_amdgcn_sched_barrier(0);
        if (i + 2 < NI) STAGE64(cur, (i + 2) * 32);

        #pragma unroll
        for (int ii = 0; ii < 2; ++ii)
            #pragma unroll
            for (int jj = 0; jj < 2; ++jj)
                acc[ii][jj] = __builtin_amdgcn_mfma_f32_16x16x32_bf16(af[ii], bfr[jj], acc[ii][jj], 0, 0, 0);
    }
#undef STAGE64

    __syncthreads();
    const int er = (lane >> 4) * 4, ec = lane & 15;
    #pragma unroll
    for (int j = 0; j < 2; ++j) {
        const int col = bn + wc*32 + j*16 + ec;
        const float bvv = bias ? bias[col & 255] : 0.0f;
        #pragma unroll
        for (int i = 0; i < 2; ++i) {
            #pragma unroll
            for (int p = 0; p < 4; ++p) {
                float val = acc[i][j][p] + bvv;
                if (ACT == 1) val = fmaxf(val, 0.0f);
                if (ACT == 2) val = 1.0f / (1.0f + __expf(-val));
                *(bf16*)&sbuf[(wr*32 + i*16 + er + p)*72 + wc*32 + j*16 + ec] = f2b(val);
            }
        }
    }
    __syncthreads();
    #pragma unroll
    for (int it = 0; it < 2; ++it) {
        const int ch = tid + it*256;
        const int row = ch >> 3, cp = (ch & 7) * 8;
        *(bf16x8*)&Cb[(size_t)(bm + row) * ldc + bn + cp] =
            *(const bf16x8*)&sbuf[row*72 + cp];
    }
}

// ---------------- fused flash attention ----------------
// grid (32 qblocks, 16 batches), 256 thr (4 waves). Wave: qg=w>>1 (16 q rows),
// ch=w&1 (128 out cols). Swapped QK^T (mfma(K,Q)) so q sits on lane&15 ->
// row softmax = 16 in-lane + shfl_xor(16,32). P -> A-operand via wave-private
// swizzled LDS bounce. K/V frags read directly from global (L2-hot). Online
// softmax with running m,l; O accumulated fp32; out = O/l -> cat1 left half.
__global__ __launch_bounds__(256) void attn_k(
    const bf16* __restrict__ qkv, const bf16* __restrict__ vtb, bf16* __restrict__ outc)
{
    __shared__ short pbuf[4096];         // 4 waves x [16 q][64 k] bf16 (swizzled)
    __shared__ short ebuf[8704];         // 4 waves x [16][136] epilogue bounce
    const int tid = threadIdx.x;
    const int lane = tid & 63, w = tid >> 6;
    const int qg = w >> 1, ch = w & 1;
    const int batch = blockIdx.y;
    const int qbase = blockIdx.x * 32 + qg * 16;
    const bf16* Qb = qkv + (size_t)batch * 786432;
    const bf16* Kb = Qb + 256;
    const bf16* Vb = vtb + (size_t)batch * 262144;
    const int fr = lane & 15, fg = lane >> 4;
    short* Pw = pbuf + w * 1024;
    short* Ew = ebuf + w * 2176;

    // hoist Q fragments (16 rows x 256 c)
    bf16x8 qf[8];
    #pragma unroll
    for (int c = 0; c < 8; ++c)
        qf[c] = *(const bf16x8*)(Qb + (size_t)(qbase + fr) * 768 + c*32 + fg*8);

    f32x4 o[8];
    #pragma unroll
    for (int i = 0; i < 8; ++i) o[i] = (f32x4){0.f, 0.f, 0.f, 0.f};
    float m_run = -INFINITY, l_run = 0.0f;

    for (int kt = 0; kt < 16; ++kt) {
        // S^T[64 k,16 q] = K_tile @ Q^T   (4 k-frags x 8 c-steps)
        f32x4 st[4];
        #pragma unroll
        for (int kf = 0; kf < 4; ++kf) {
            st[kf] = (f32x4){0.f, 0.f, 0.f, 0.f};
            #pragma unroll
            for (int c = 0; c < 8; ++c) {
                bf16x8 kfrag = *(const bf16x8*)(Kb + (size_t)(kt*64 + kf*16 + fr) * 768 + c*32 + fg*8);
                st[kf] = __builtin_amdgcn_mfma_f32_16x16x32_bf16(kfrag, qf[c], st[kf], 0, 0, 0);
            }
        }
        // scale + tile row-max (per q=fr; lane holds k = kf*16 + fg*4 + r)
        float tm = -INFINITY;
        #pragma unroll
        for (int kf = 0; kf < 4; ++kf)
            #pragma unroll
            for (int r = 0; r < 4; ++r) {
                st[kf][r] *= 0.0625f;
                tm = fmaxf(tm, st[kf][r]);
            }
        tm = fmaxf(tm, __shfl_xor(tm, 16));
        tm = fmaxf(tm, __shfl_xor(tm, 32));
        const float m_new = fmaxf(m_run, tm);
        const float sf = __expf(m_run - m_new);      // 0 on first tile
        float ts = 0.0f;
        float p[16];
        #pragma unroll
        for (int kf = 0; kf < 4; ++kf)
            #pragma unroll
            for (int r = 0; r < 4; ++r) {
                const float e = __expf(st[kf][r] - m_new);
                p[kf*4 + r] = e; ts += e;
            }
        ts += __shfl_xor(ts, 16);
        ts += __shfl_xor(ts, 32);
        l_run = l_run * sf + ts;
        m_run = m_new;
        // rescale O (O rows q = fg*4 + r; stats live at lane index q in 0..15)
        float sfr[4];
        #pragma unroll
        for (int r = 0; r < 4; ++r) sfr[r] = __shfl(sf, fg*4 + r);
        #pragma unroll
        for (int cf = 0; cf < 8; ++cf)
            #pragma unroll
            for (int r = 0; r < 4; ++r) o[cf][r] *= sfr[r];
        // P -> wave-private LDS, swizzled: octet o = kf*2 + (fg>>1), o' = o ^ ((fr>>1)&3)
        asm volatile("s_waitcnt lgkmcnt(0)" ::: "memory");   // prior tile's reads done
        #pragma unroll
        for (int kf = 0; kf < 4; ++kf) {
            const int oswz = (kf*2 + (fg>>1)) ^ ((fr>>1)&3);
            #pragma unroll
            for (int rp = 0; rp < 2; ++rp) {
                const unsigned pk = (unsigned)f2bu(p[kf*4 + rp*2])
                                  | ((unsigned)f2bu(p[kf*4 + rp*2 + 1]) << 16);
                ((unsigned*)Pw)[fr*32 + oswz*4 + (fg&1)*2 + rp] = pk;
            }
        }
        asm volatile("s_waitcnt lgkmcnt(0)" ::: "memory");
        __builtin_amdgcn_sched_barrier(0);
        bf16x8 pa[2];
        #pragma unroll
        for (int ks = 0; ks < 2; ++ks)
            pa[ks] = *(const bf16x8*)&Pw[fr*64 + (((ks*4 + fg) ^ ((fr>>1)&3)))*8];
        asm volatile("s_waitcnt lgkmcnt(0)" ::: "memory");
        __builtin_amdgcn_sched_barrier(0);
        // O += P @ V_tile  (8 c-frags x 2 k-steps), V from vtb rows (c-major)
        #pragma unroll
        for (int cf = 0; cf < 8; ++cf)
            #pragma unroll
            for (int ks = 0; ks < 2; ++ks) {
                bf16x8 vfrag = *(const bf16x8*)(Vb + (size_t)(ch*128 + cf*16 + fr) * 1024 + kt*64 + ks*32 + fg*8);
                o[cf] = __builtin_amdgcn_mfma_f32_16x16x32_bf16(pa[ks], vfrag, o[cf], 0, 0, 0);
            }
    }

    // epilogue: O/l -> LDS bounce -> coalesced 16B stores into cat1 left half
    float linv[4];
    #pragma unroll
    for (int r = 0; r < 4; ++r) linv[r] = 1.0f / __shfl(l_run, fg*4 + r);
    #pragma unroll
    for (int cf = 0; cf < 8; ++cf)
        #pragma unroll
        for (int r = 0; r < 4; ++r)
            Ew[(fg*4 + r)*136 + cf*16 + fr] = (short)f2bu(o[cf][r] * linv[r]);
    asm volatile("s_waitcnt lgkmcnt(0)" ::: "memory");
    __builtin_amdgcn_sched_barrier(0);
    #pragma unroll
    for (int it = 0; it < 4; ++it) {
        const int cidx = it*64 + lane;
        const int row = cidx >> 4, cp = (cidx & 15) * 8;
        *(bf16x8*)&outc[(size_t)(batch*1024 + qbase + row) * 512 + ch*128 + cp] =
            *(const bf16x8*)&Ew[row*136 + cp];
    }
}

// ---------------- all weight transposes fp32[K,Nn] -> bf16[Nn,K], one dispatch ----------------
__global__ __launch_bounds__(256) void prep_w_k(
    const float* __restrict__ Wq, const float* __restrict__ Wk, const float* __restrict__ Wv,
    const float* __restrict__ Wg, const float* __restrict__ Wm, const float* __restrict__ Wc1,
    const float* __restrict__ Wrel, const float* __restrict__ Wroot, bf16* __restrict__ WT)
{
    int t = blockIdx.x;
    const float* in; bf16* out; int K, Nn;
    if (t < 192)      { int wsel = t >> 6; t &= 63;
                        in = wsel == 0 ? Wq : (wsel == 1 ? Wk : Wv);
                        out = WT + wsel*65536; K = 256; Nn = 256; }
    else if (t < 320) { t -= 192; in = Wg;  out = WT + 196608; K = 512; Nn = 256; }
    else if (t < 448) { t -= 320; in = Wm;  out = WT + 327680; K = 512; Nn = 256; }
    else if (t < 480) { t -= 448; in = Wc1; out = WT + 458752; K = 256; Nn = 128; }
    else if (t < 992) { t -= 480; int r = t >> 6; t &= 63;
                        in = Wrel + (size_t)r*65536; out = WT + 491520 + r*65536; K = 256; Nn = 256; }
    else              { t -= 992; in = Wroot; out = WT + 491520 + 524288; K = 256; Nn = 256; }
    const int tpr = Nn >> 5;
    const int n0 = (t % tpr) * 32, k0 = (t / tpr) * 32;
    __shared__ float tile[32][33];
    const int tx = threadIdx.x & 31, ty = threadIdx.x >> 5;
    #pragma unroll
    for (int i = 0; i < 4; ++i) {
        int r = ty + i*8;
        tile[r][tx] = in[(size_t)(k0 + r) * Nn + n0 + tx];
    }
    __syncthreads();
    #pragma unroll
    for (int i = 0; i < 4; ++i) {
        int r = ty + i*8;
        out[(size_t)(n0 + r) * K + k0 + tx] = f2b(tile[tx][r]);
    }
}

// ---------------- V^T: qkv V-part [1024,256] (ld 768) -> vtb [256,1024] per batch ----------------
__global__ __launch_bounds__(256) void vtrans_k(
    const bf16* __restrict__ in, bf16* __restrict__ out)
{
    __shared__ float tile[32][33];
    in  += (size_t)blockIdx.z * 786432 + 512;
    out += (size_t)blockIdx.z * 262144;
    const int n0 = blockIdx.x * 32, k0 = blockIdx.y * 32;
    const int tx = threadIdx.x & 31, ty = threadIdx.x >> 5;
    #pragma unroll
    for (int i = 0; i < 4; ++i) {
        int r = ty + i*8;
        tile[r][tx] = b2f(in[(size_t)(k0 + r) * 768 + n0 + tx]);
    }
    __syncthreads();
    #pragma unroll
    for (int i = 0; i < 4; ++i) {
        int r = ty + i*8;
        out[(size_t)(n0 + r) * 1024 + k0 + tx] = f2b(tile[tx][r]);
    }
}

// ---------------- x fp32 -> bf16 (xb, cat1 right half, cat2 left half), 4 el/thread ----------------
__global__ __launch_bounds__(256) void cvt_x_k(const float* __restrict__ x,
    bf16* __restrict__ xb, bf16* __restrict__ cat1, bf16* __restrict__ cat2)
{
    const int i4 = (blockIdx.x * 256 + threadIdx.x) * 4;
    const float4 xv = *(const float4*)(x + i4);
    bf16 bv[4] = { f2b(xv.x), f2b(xv.y), f2b(xv.z), f2b(xv.w) };
    const ushort4 pack = *(const ushort4*)bv;
    const int row = i4 >> 8, col = i4 & 255;
    *(ushort4*)(xb + i4) = pack;
    *(ushort4*)(cat1 + (size_t)row * 512 + 256 + col) = pack;
    *(ushort4*)(cat2 + (size_t)row * 512 + col) = pack;
}

// ---------------- LN over C=256 (wave per row, 4 ch/lane), bf16 in/out ----------------
template<int RELU>
__global__ __launch_bounds__(256) void ln_k(
    const bf16* __restrict__ in, bf16* __restrict__ out,
    const float* __restrict__ g, const float* __restrict__ bta)
{
    const int node = blockIdx.x * 4 + (threadIdx.x >> 6);
    const int lane = threadIdx.x & 63;
    const ushort4 iv = *(const ushort4*)(in + (size_t)node * 256 + lane * 4);
    float v0 = us2f(iv.x), v1 = us2f(iv.y), v2 = us2f(iv.z), v3 = us2f(iv.w);
    float s  = v0 + v1 + v2 + v3;
    float sq = v0*v0 + v1*v1 + v2*v2 + v3*v3;
    #pragma unroll
    for (int o = 32; o >= 1; o >>= 1) { s += __shfl_xor(s, o); sq += __shfl_xor(sq, o); }
    const float mean = s * (1.0f / 256.0f);
    const float var  = sq * (1.0f / 256.0f) - mean * mean;
    const float rs = rsqrtf(var + 1e-5f);
    const float4 gv = *(const float4*)(g + lane * 4);
    const float4 bv = *(const float4*)(bta + lane * 4);
    float y0 = (v0 - mean) * rs * gv.x + bv.x;
    float y1 = (v1 - mean) * rs * gv.y + bv.y;
    float y2 = (v2 - mean) * rs * gv.z + bv.z;
    float y3 = (v3 - mean) * rs * gv.w + bv.w;
    if (RELU) { y0 = fmaxf(y0, 0.f); y1 = fmaxf(y1, 0.f); y2 = fmaxf(y2, 0.f); y3 = fmaxf(y3, 0.f); }
    bf16 ov[4] = { f2b(y0), f2b(y1), f2b(y2), f2b(y3) };
    *(ushort4*)(out + (size_t)node * 256 + lane * 4) = *(const ushort4*)ov;
}

// ---------------- gated blend + LN (wave per row) ----------------
__global__ __launch_bounds__(256) void blend_ln_k(
    const bf16* __restrict__ gate, const bf16* __restrict__ cat1,
    const float* __restrict__ x, bf16* __restrict__ valid,
    const float* __restrict__ g, const float* __restrict__ bta)
{
    const int node = blockIdx.x * 4 + (threadIdx.x >> 6);
    const int lane = threadIdx.x & 63;
    const ushort4 gt4 = *(const ushort4*)(gate + (size_t)node * 256 + lane * 4);
    const ushort4 ao4 = *(const ushort4*)(cat1 + (size_t)node * 512 + lane * 4);
    const float4  xv4 = *(const float4*)(x + (size_t)node * 256 + lane * 4);
    float g0 = us2f(gt4.x), g1 = us2f(gt4.y), g2 = us2f(gt4.z), g3 = us2f(gt4.w);
    float v0 = g0 * us2f(ao4.x) + (1.f - g0) * xv4.x;
    float v1 = g1 * us2f(ao4.y) + (1.f - g1) * xv4.y;
    float v2 = g2 * us2f(ao4.z) + (1.f - g2) * xv4.z;
    float v3 = g3 * us2f(ao4.w) + (1.f - g3) * xv4.w;
    float s  = v0 + v1 + v2 + v3;
    float sq = v0*v0 + v1*v1 + v2*v2 + v3*v3;
    #pragma unroll
    for (int o = 32; o >= 1; o >>= 1) { s += __shfl_xor(s, o); sq += __shfl_xor(sq, o); }
    const float mean = s * (1.0f / 256.0f);
    const float var  = sq * (1.0f / 256.0f) - mean * mean;
    const float rs = rsqrtf(var + 1e-5f);
    const float4 gv = *(const float4*)(g + lane * 4);
    const float4 bv = *(const float4*)(bta + lane * 4);
    bf16 ov[4] = { f2b((v0 - mean) * rs * gv.x + bv.x), f2b((v1 - mean) * rs * gv.y + bv.y),
                   f2b((v2 - mean) * rs * gv.z + bv.z), f2b((v3 - mean) * rs * gv.w + bv.w) };
    *(ushort4*)(valid + (size_t)node * 256 + lane * 4) = *(const ushort4*)ov;
}

// ---------------- confidence layer2 + weighted (wave per node) ----------------
__global__ __launch_bounds__(256) void conf_w_k(
    const bf16* __restrict__ t1, const float* __restrict__ Wc2, const float* __restrict__ bc2,
    const bf16* __restrict__ valid, float* __restrict__ conf, bf16* __restrict__ cat2)
{
    const int node = blockIdx.x * 4 + (threadIdx.x >> 6);
    const int lane = threadIdx.x & 63;
    float a = b2f(t1[(size_t)node * 128 + lane]) * Wc2[lane]
            + b2f(t1[(size_t)node * 128 + 64 + lane]) * Wc2[64 + lane];
    #pragma unroll
    for (int o = 32; o >= 1; o >>= 1) a += __shfl_xor(a, o);
    const float c = 1.0f / (1.0f + __expf(-(a + bc2[0])));
    if (lane == 0) conf[node] = c;
    const ushort4 vv = *(const ushort4*)(valid + (size_t)node * 256 + lane * 4);
    bf16 ov[4] = { f2b(us2f(vv.x) * c), f2b(us2f(vv.y) * c), f2b(us2f(vv.z) * c), f2b(us2f(vv.w) * c) };
    *(ushort4*)(cat2 + (size_t)node * 512 + 256 + lane * 4) = *(const ushort4*)ov;
}

// ---------------- CSR build ----------------
__global__ __launch_bounds__(256) void count2_k(
    const int* __restrict__ dst, const int* __restrict__ et,
    int* __restrict__ deg, int* __restrict__ cnt8)
{
    const int e = blockIdx.x * 256 + threadIdx.x;
    if (e < E_) {
        const int d = dst[e];
        atomicAdd(&deg[d], 1);
        atomicAdd(&cnt8[d * 8 + et[e]], 1);
    }
}

__global__ __launch_bounds__(256) void scan_k(
    const int* __restrict__ deg, int* __restrict__ rowptr, int* __restrict__ cursor)
{
    __shared__ int part[256];
    const int tid = threadIdx.x;
    const int base = tid * 64;
    int s = 0;
    for (int i = 0; i < 64; ++i) s += deg[base + i];
    part[tid] = s; __syncthreads();
    for (int off = 1; off < 256; off <<= 1) {
        int t = (tid >= off) ? part[tid - off] : 0;
        __syncthreads();
        part[tid] += t;
        __syncthreads();
    }
    int run = (tid == 0) ? 0 : part[tid - 1];
    for (int i = 0; i < 64; ++i) {
        rowptr[base + i] = run;
        cursor[base + i] = run;
        run += deg[base + i];
    }
    if (tid == 255) rowptr[BN_] = run;
}

__global__ __launch_bounds__(256) void fill_k(
    const int* __restrict__ src, const int* __restrict__ dst, const int* __restrict__ et,
    int* __restrict__ cursor, int* __restrict__ elist)
{
    const int e = blockIdx.x * 256 + threadIdx.x;
    if (e < E_) {
        const int pos = atomicAdd(&cursor[dst[e]], 1);
        elist[pos] = src[e] | (et[e] << 16);
    }
}

// ---------------- RGCN gather + root + bias + LN2 + relu (wave per node) ----------------
__global__ __launch_bounds__(256) void gather_ln_k(
    const int* __restrict__ rowptr, const int* __restrict__ elist,
    const bf16* __restrict__ h, const int* __restrict__ cnt8,
    const float* __restrict__ brg,
    const float* __restrict__ g, const float* __restrict__ bta,
    bf16* __restrict__ xr)
{
    const int node = blockIdx.x * 4 + (threadIdx.x >> 6);
    const int lane = threadIdx.x & 63;
    const int e0 = rowptr[node], e1 = rowptr[node + 1];
    float invc[8];
    #pragma unroll
    for (int r = 0; r < 8; ++r)
        invc[r] = 1.0f / fmaxf((float)cnt8[node * 8 + r], 1.0f);
    float a0 = 0.f, a1 = 0.f, a2 = 0.f, a3 = 0.f;
    for (int e = e0; e < e1; ++e) {
        const int pe = elist[e];
        const int srcn = pe & 0xffff, rel = pe >> 16;
        const float wgt = invc[rel];
        const ushort4 hv = *(const ushort4*)(h + (size_t)srcn * 2304 + rel * 256 + lane * 4);
        a0 += wgt * us2f(hv.x); a1 += wgt * us2f(hv.y);
        a2 += wgt * us2f(hv.z); a3 += wgt * us2f(hv.w);
    }
    const ushort4 rv = *(const ushort4*)(h + (size_t)node * 2304 + 2048 + lane * 4);
    const float4 bg4 = *(const float4*)(brg + lane * 4);
    const float v0 = a0 + us2f(rv.x) + bg4.x, v1 = a1 + us2f(rv.y) + bg4.y;
    const float v2 = a2 + us2f(rv.z) + bg4.z, v3 = a3 + us2f(rv.w) + bg4.w;
    float s  = v0 + v1 + v2 + v3;
    float sq = v0*v0 + v1*v1 + v2*v2 + v3*v3;
    #pragma unroll
    for (int m = 32; m >= 1; m >>= 1) { s += __shfl_xor(s, m); sq += __shfl_xor(sq, m); }
    const float mean = s * (1.0f / 256.0f);
    const float var  = sq * (1.0f / 256.0f) - mean * mean;
    const float rs = rsqrtf(var + 1e-5f);
    const float4 gv = *(const float4*)(g + lane * 4);
    const float4 bv = *(const float4*)(bta + lane * 4);
    bf16 tb[4] = { f2b(fmaxf((v0 - mean) * rs * gv.x + bv.x, 0.f)),
                   f2b(fmaxf((v1 - mean) * rs * gv.y + bv.y, 0.f)),
                   f2b(fmaxf((v2 - mean) * rs * gv.z + bv.z, 0.f)),
                   f2b(fmaxf((v3 - mean) * rs * gv.w + bv.w, 0.f)) };
    *(ushort4*)(xr + (size_t)node * 256 + lane * 4) = *(const ushort4*)tb;
}

// ---------------- pooling stage 1 ----------------
__global__ __launch_bounds__(256) void pool1_k(
    const bf16* __restrict__ xr, const float* __restrict__ conf, float* __restrict__ partial)
{
    const int b = blockIdx.x, chunk = blockIdx.y, c = threadIdx.x;
    float acc = 0.0f;
    for (int n = 0; n < 64; ++n) {
        const int node = b * 1024 + chunk * 64 + n;
        acc += conf[node] * b2f(xr[(size_t)node * 256 + c]);
    }
    partial[(size_t)(b * 16 + chunk) * 256 + c] = acc;
}

// ---------------- pooling stage 2 + head ----------------
__global__ __launch_bounds__(256) void pool2_k(
    const float* __restrict__ partial, const float* __restrict__ conf,
    const float* __restrict__ Wh, const float* __restrict__ bh, float* __restrict__ out)
{
    const int b = blockIdx.x, tid = threadIdx.x;
    __shared__ float red[256];
    __shared__ float pooled[256];
    float pc = 0.0f;
    for (int ch = 0; ch < 16; ++ch) pc += partial[(size_t)(b * 16 + ch) * 256 + tid];
    float s = conf[b * 1024 + tid] + conf[b * 1024 + 256 + tid]
            + conf[b * 1024 + 512 + tid] + conf[b * 1024 + 768 + tid];
    red[tid] = s; __syncthreads();
    for (int st = 128; st > 0; st >>= 1) { if (tid < st) red[tid] += red[tid + st]; __syncthreads(); }
    const float denom = fmaxf(red[0], 1e-8f);
    pooled[tid] = pc / denom;
    __syncthreads();
    if (tid < NS_) {
        float o = bh[tid];
        for (int c = 0; c < 256; ++c) o += pooled[c] * Wh[c * NS_ + tid];
        out[b * NS_ + tid] = o;
    }
}

extern "C" void kernel_launch(void* const* d_in, const int* in_sizes, int n_in,
                              void* d_out, int out_size, void* d_ws, size_t ws_size,
                              hipStream_t stream) {
    const float* x    = (const float*)d_in[0];
    const int*   ei   = (const int*)d_in[1];
    const int*   et   = (const int*)d_in[2];
    const float* Wq   = (const float*)d_in[3];  const float* bq  = (const float*)d_in[4];
    const float* Wk   = (const float*)d_in[5];  const float* bk  = (const float*)d_in[6];
    const float* Wv   = (const float*)d_in[7];  const float* bv  = (const float*)d_in[8];
    const float* Wg   = (const float*)d_in[9];  const float* bg  = (const float*)d_in[10];
    const float* lag  = (const float*)d_in[11]; const float* lab = (const float*)d_in[12];
    const float* Wc1  = (const float*)d_in[13]; const float* bc1 = (const float*)d_in[14];
    const float* Wc2  = (const float*)d_in[15]; const float* bc2 = (const float*)d_in[16];
    const float* Wm   = (const float*)d_in[17]; const float* bm  = (const float*)d_in[18];
    const float* l1g  = (const float*)d_in[19]; const float* l1b = (const float*)d_in[20];
    const float* Wrel = (const float*)d_in[21]; const float* Wroot = (const float*)d_in[22];
    const float* brg  = (const float*)d_in[23];
    const float* l2g  = (const float*)d_in[24]; const float* l2b = (const float*)d_in[25];
    const float* Wh   = (const float*)d_in[26]; const float* bh  = (const float*)d_in[27];
    const int* esrc = ei;
    const int* edst = ei + E_;

    char* w8 = (char*)d_ws;
    bf16*  qkv   = (bf16*)(w8 + 0);
    bf16*  hbuf  = (bf16*)(w8 + 0);
    bf16*  cat1  = (bf16*)(w8 + 58720256);
    bf16*  cat2  = (bf16*)(w8 + 75497472);
    bf16*  gate  = (bf16*)(w8 + 92274688);
    bf16*  valid = (bf16*)(w8 + 100663296);
    bf16*  t1    = (bf16*)(w8 + 109051904);
    bf16*  xm    = (bf16*)(w8 + 113246208);
    bf16*  xb    = (bf16*)(w8 + 121634816);
    bf16*  xn    = (bf16*)(w8 + 130023424);
    bf16*  vtb   = (bf16*)(w8 + 138412032);
    bf16*  xr    = (bf16*)(w8 + 146800640);
    float* conf  = (float*)(w8 + 155189248);
    float* part  = (float*)(w8 + 155254784);
    bf16*  WT    = (bf16*)(w8 + 155516928);
    int*  deg    = (int*)(w8 + 157679616);
    int*  cnt8i  = (int*)(w8 + 157745152);
    int*  rowptr = (int*)(w8 + 158269440);
    int*  cursor = (int*)(w8 + 158335232);
    int*  elist  = (int*)(w8 + 158400768);
    bf16* WqkvT = WT;                  // [768,256]
    bf16* WgT   = WT + 196608;         // [256,512]
    bf16* WmT   = WT + 327680;         // [256,512]
    bf16* Wc1T  = WT + 458752;         // [128,256]
    bf16* WBIG  = WT + 491520;         // [2304,256]
    float* outp = (float*)d_out;

    dim3 blk(256);

    // --- prep: weights (1 dispatch), x conversion, CSR build ---
    prep_w_k<<<1056, blk, 0, stream>>>(Wq, Wk, Wv, Wg, Wm, Wc1, Wrel, Wroot, WT);
    cvt_x_k<<<BNC_ / 1024, blk, 0, stream>>>(x, xb, cat1, cat2);
    hipMemsetAsync(deg, 0, 589824, stream);
    count2_k<<<E_ / 256, blk, 0, stream>>>(edst, et, deg, cnt8i);
    scan_k<<<1, blk, 0, stream>>>(deg, rowptr, cursor);
    fill_k<<<E_ / 256, blk, 0, stream>>>(esrc, edst, et, cursor, elist);

    // --- fused QKV projection: qkv[16384,768] ---
    gemm_bf16<0><<<dim3(6, 128, 1), blk, 0, stream>>>(
        xb, 256, 0, WqkvT, 256, 0, qkv, 768, 0, bq, bk, bv, 256);
    vtrans_k<<<dim3(8, 32, 16), blk, 0, stream>>>(qkv, vtb);

    // --- fused flash attention -> cat1 left half ---
    attn_k<<<dim3(32, 16), blk, 0, stream>>>(qkv, vtb, cat1);

    // --- gate (64-tile), blend+LN ---
    gemm64_bf16<2><<<dim3(4, 256, 1), blk, 0, stream>>>(
        cat1, 512, 0, WgT, 512, 0, gate, 256, 0, bg, 512);
    blend_ln_k<<<BN_ / 4, blk, 0, stream>>>(gate, cat1, x, valid, lag, lab);

    // --- confidence (64-tile) + weighted ---
    gemm64_bf16<1><<<dim3(2, 256, 1), blk, 0, stream>>>(
        valid, 256, 0, Wc1T, 256, 0, t1, 128, 0, bc1, 256);
    conf_w_k<<<BN_ / 4, blk, 0, stream>>>(t1, Wc2, bc2, valid, conf, cat2);

    // --- mixer (64-tile) + LN1 ---
    gemm64_bf16<1><<<dim3(4, 256, 1), blk, 0, stream>>>(
        cat2, 512, 0, WmT, 512, 0, xm, 256, 0, bm, 512);
    ln_k<0><<<BN_ / 4, blk, 0, stream>>>(xm, xn, l1g, l1b);

    // --- RGCN: one GEMM (128-tile, 2304 blocks), gather + LN2 ---
    gemm_bf16<0><<<dim3(18, 128, 1), blk, 0, stream>>>(
        xn, 256, 0, WBIG, 256, 0, hbuf, 2304, 0, nullptr, nullptr, nullptr, 256);
    gather_ln_k<<<BN_ / 4, blk, 0, stream>>>(rowptr, elist, hbuf, cnt8i, brg, l2g, l2b, xr);

    // --- pool + head ---
    pool1_k<<<dim3(B_, 16), blk, 0, stream>>>(xr, conf, part);
    pool2_k<<<B_, blk, 0, stream>>>(part, conf, Wh, bh, outp);
}

// Round 10
// 279.861 us; speedup vs baseline: 1.4119x; 1.4119x over previous
//
#include <hip/hip_runtime.h>
#include <hip/hip_bf16.h>

#define B_ 16
#define N_ 1024
#define C_ 256
#define R_ 8
#define E_ 262144
#define NS_ 32
#define BN_ (B_*N_)
#define BNC_ (BN_*C_)

typedef __hip_bfloat16 bf16;
typedef __attribute__((ext_vector_type(4))) float f32x4;
typedef __attribute__((ext_vector_type(8))) short bf16x8;

__device__ __forceinline__ float b2f(bf16 x) { return __bfloat162float(x); }
__device__ __forceinline__ bf16  f2b(float x) { return __float2bfloat16(x); }
__device__ __forceinline__ float us2f(unsigned short u) { return __uint_as_float((unsigned)u << 16); }

// async global->LDS, 16B per lane (wave-uniform LDS base + lane*16 implicit)
__device__ __forceinline__ void gload16(const void* g, void* l) {
    auto gp = (const __attribute__((address_space(1))) void*)(unsigned long long)g;
    auto lp = (__attribute__((address_space(3))) void*)(unsigned)(unsigned long long)l;
    __builtin_amdgcn_global_load_lds(gp, lp, 16, 0, 0);
}

// ---------------- bf16 MFMA GEMM (128x128 tile): C = act(A @ B^T + bias) ----------------
// Depth-2 pipeline, counted vmcnt(4); XOR slot swizzle both sides (rule #21).
// T1 XCD-aware block swizzle: per-z-slice nwg divisible by 8 for every grid used
// here, so (id%8)*(nwg/8)+id/8 is bijective; each XCD gets a contiguous tile
// chunk -> operand panels become L2-resident (targets RGCN A re-fetch).
template<int ACT>
__global__ __launch_bounds__(256) void gemm_bf16(
    const bf16* __restrict__ A, int lda, long long sA,
    const bf16* __restrict__ Bm, int ldb, long long sB,
    bf16* __restrict__ Cc, int ldc, long long sC,
    const float* __restrict__ bias, const float* __restrict__ bias2,
    const float* __restrict__ bias3, int K)
{
    __shared__ short sbuf[16384];        // 32 KB
    const int tid = threadIdx.x;
    const int lane = tid & 63, w = tid >> 6;
    const int wr = w >> 1, wc = w & 1;

    // XCD swizzle (bijective when nwg % 8 == 0; identity otherwise)
    const int gx = gridDim.x;
    const int nwg = gx * gridDim.y;
    int id = blockIdx.y * gx + blockIdx.x;
    if ((nwg & 7) == 0) { const int cpx = nwg >> 3; id = (id & 7) * cpx + (id >> 3); }
    const int bm = (id / gx) * 128, bn = (id % gx) * 128;

    const bf16* Ab = A + (size_t)blockIdx.z * sA;
    const bf16* Bb = Bm + (size_t)blockIdx.z * sB;
    bf16* Cb = Cc + (size_t)blockIdx.z * sC;

    const int rg = lane >> 2;
    const int kswz = ((lane & 3) ^ ((rg >> 1) & 3)) * 8;

    f32x4 acc[4][4];
    const f32x4 zz = {0.f, 0.f, 0.f, 0.f};
    #pragma unroll
    for (int i = 0; i < 4; ++i)
        #pragma unroll
        for (int j = 0; j < 4; ++j) acc[i][j] = zz;

    const int fr = lane & 15;
    const int fm = lane >> 4;
    const int fslot = (fm ^ ((fr >> 1) & 3)) * 8;

    const int NI = K >> 5;

#define STAGE_AB(bi, kk) do {                                                          \
    _Pragma("unroll")                                                                  \
    for (int t_ = 0; t_ < 2; ++t_) {                                                   \
        gload16(Ab + (size_t)(bm + t_*64 + w*16 + rg) * lda + (kk) + kswz,             \
                sbuf + (bi)*4096 + t_*2048 + w*512);                                   \
        gload16(Bb + (size_t)(bn + t_*64 + w*16 + rg) * ldb + (kk) + kswz,             \
                sbuf + 8192 + (bi)*4096 + t_*2048 + w*512);                            \
    } } while (0)

    STAGE_AB(0, 0);
    if (NI > 1) STAGE_AB(1, 32);

    for (int i = 0; i < NI; ++i) {
        const int cur = i & 1;
        if (i + 1 < NI) asm volatile("s_waitcnt vmcnt(4)" ::: "memory");
        else            asm volatile("s_waitcnt vmcnt(0)" ::: "memory");
        __builtin_amdgcn_s_barrier();
        __builtin_amdgcn_sched_barrier(0);

        bf16x8 af[4], bfr[4];
        const short* Ac = sbuf + cur * 4096;
        const short* Bc = sbuf + 8192 + cur * 4096;
        #pragma unroll
        for (int ii = 0; ii < 4; ++ii)
            af[ii] = *(const bf16x8*)&Ac[(wr*64 + ii*16 + fr)*32 + fslot];
        #pragma unroll
        for (int jj = 0; jj < 4; ++jj)
            bfr[jj] = *(const bf16x8*)&Bc[(wc*64 + jj*16 + fr)*32 + fslot];

        asm volatile("s_waitcnt lgkmcnt(0)" ::: "memory");
        __builtin_amdgcn_s_barrier();
        __builtin_amdgcn_sched_barrier(0);
        if (i + 2 < NI) STAGE_AB(cur, (i + 2) * 32);

        #pragma unroll
        for (int ii = 0; ii < 4; ++ii)
            #pragma unroll
            for (int jj = 0; jj < 4; ++jj)
                acc[ii][jj] = __builtin_amdgcn_mfma_f32_16x16x32_bf16(af[ii], bfr[jj], acc[ii][jj], 0, 0, 0);
    }
#undef STAGE_AB

    __syncthreads();
    const int er = (lane >> 4) * 4, ec = lane & 15;
    #pragma unroll
    for (int half = 0; half < 2; ++half) {
        if (wr == half) {
            #pragma unroll
            for (int j = 0; j < 4; ++j) {
                const int col = bn + wc*64 + j*16 + ec;
                float bvv = 0.0f;
                if (bias) {
                    const int seg = col >> 8;
                    const float* bp = (seg == 0) ? bias : (seg == 1 ? bias2 : bias3);
                    bvv = bp[col & 255];
                }
                #pragma unroll
                for (int i = 0; i < 4; ++i) {
                    #pragma unroll
                    for (int p = 0; p < 4; ++p) {
                        float val = acc[i][j][p] + bvv;
                        if (ACT == 1) val = fmaxf(val, 0.0f);
                        if (ACT == 2) val = 1.0f / (1.0f + __expf(-val));
                        *(bf16*)&sbuf[(i*16 + er + p)*136 + wc*64 + j*16 + ec] = f2b(val);
                    }
                }
            }
        }
        __syncthreads();
        #pragma unroll
        for (int it = 0; it < 4; ++it) {
            const int ch = tid + it*256;
            const int row = ch >> 4, cp = (ch & 15) * 8;
            *(bf16x8*)&Cb[(size_t)(bm + half*64 + row) * ldc + bn + cp] =
                *(const bf16x8*)&sbuf[row*136 + cp];
        }
        __syncthreads();
    }
}

// ---------------- all weight transposes fp32[K,Nn] -> bf16[Nn,K], one dispatch ----------------
__global__ __launch_bounds__(256) void prep_w_k(
    const float* __restrict__ Wq, const float* __restrict__ Wk, const float* __restrict__ Wv,
    const float* __restrict__ Wg, const float* __restrict__ Wm, const float* __restrict__ Wc1,
    const float* __restrict__ Wrel, const float* __restrict__ Wroot, bf16* __restrict__ WT)
{
    int t = blockIdx.x;
    const float* in; bf16* out; int K, Nn;
    if (t < 192)      { int wsel = t >> 6; t &= 63;
                        in = wsel == 0 ? Wq : (wsel == 1 ? Wk : Wv);
                        out = WT + wsel*65536; K = 256; Nn = 256; }
    else if (t < 320) { t -= 192; in = Wg;  out = WT + 196608; K = 512; Nn = 256; }
    else if (t < 448) { t -= 320; in = Wm;  out = WT + 327680; K = 512; Nn = 256; }
    else if (t < 480) { t -= 448; in = Wc1; out = WT + 458752; K = 256; Nn = 128; }
    else if (t < 992) { t -= 480; int r = t >> 6; t &= 63;
                        in = Wrel + (size_t)r*65536; out = WT + 491520 + r*65536; K = 256; Nn = 256; }
    else              { t -= 992; in = Wroot; out = WT + 491520 + 524288; K = 256; Nn = 256; }
    const int tpr = Nn >> 5;
    const int n0 = (t % tpr) * 32, k0 = (t / tpr) * 32;
    __shared__ float tile[32][33];
    const int tx = threadIdx.x & 31, ty = threadIdx.x >> 5;
    #pragma unroll
    for (int i = 0; i < 4; ++i) {
        int r = ty + i*8;
        tile[r][tx] = in[(size_t)(k0 + r) * Nn + n0 + tx];
    }
    __syncthreads();
    #pragma unroll
    for (int i = 0; i < 4; ++i) {
        int r = ty + i*8;
        out[(size_t)(n0 + r) * K + k0 + tx] = f2b(tile[tx][r]);
    }
}

// ---------------- V^T: qkv V-part [1024,256] (ld 768) -> vtb [256,1024] per batch ----------------
__global__ __launch_bounds__(256) void vtrans_k(
    const bf16* __restrict__ in, bf16* __restrict__ out)
{
    __shared__ float tile[32][33];
    in  += (size_t)blockIdx.z * 786432 + 512;
    out += (size_t)blockIdx.z * 262144;
    const int n0 = blockIdx.x * 32, k0 = blockIdx.y * 32;
    const int tx = threadIdx.x & 31, ty = threadIdx.x >> 5;
    #pragma unroll
    for (int i = 0; i < 4; ++i) {
        int r = ty + i*8;
        tile[r][tx] = b2f(in[(size_t)(k0 + r) * 768 + n0 + tx]);
    }
    __syncthreads();
    #pragma unroll
    for (int i = 0; i < 4; ++i) {
        int r = ty + i*8;
        out[(size_t)(n0 + r) * 1024 + k0 + tx] = f2b(tile[tx][r]);
    }
}

// ---------------- x fp32 -> bf16 (xb, cat1 right half, cat2 left half), 4 el/thread ----------------
__global__ __launch_bounds__(256) void cvt_x_k(const float* __restrict__ x,
    bf16* __restrict__ xb, bf16* __restrict__ cat1, bf16* __restrict__ cat2)
{
    const int i4 = (blockIdx.x * 256 + threadIdx.x) * 4;
    const float4 xv = *(const float4*)(x + i4);
    bf16 bv[4] = { f2b(xv.x), f2b(xv.y), f2b(xv.z), f2b(xv.w) };
    const ushort4 pack = *(const ushort4*)bv;
    const int row = i4 >> 8, col = i4 & 255;
    *(ushort4*)(xb + i4) = pack;
    *(ushort4*)(cat1 + (size_t)row * 512 + 256 + col) = pack;
    *(ushort4*)(cat2 + (size_t)row * 512 + col) = pack;
}

// ---------------- row softmax over 1024 bf16 scores in place (pre-scale 1/16) ----------------
__global__ __launch_bounds__(256) void softmax_k(bf16* __restrict__ s)
{
    const int row = blockIdx.x, tid = threadIdx.x;
    const int lane = tid & 63, wid = tid >> 6;
    bf16* rp = s + (size_t)row * 1024 + tid * 4;
    __shared__ float red[8];
    const ushort4 sv = *(const ushort4*)rp;
    float v0 = us2f(sv.x) * 0.0625f, v1 = us2f(sv.y) * 0.0625f;
    float v2 = us2f(sv.z) * 0.0625f, v3 = us2f(sv.w) * 0.0625f;
    float m = fmaxf(fmaxf(v0, v1), fmaxf(v2, v3));
    #pragma unroll
    for (int o = 32; o >= 1; o >>= 1) m = fmaxf(m, __shfl_xor(m, o));
    if (lane == 0) red[wid] = m;
    __syncthreads();
    const float mx = fmaxf(fmaxf(red[0], red[1]), fmaxf(red[2], red[3]));
    float e0 = __expf(v0 - mx), e1 = __expf(v1 - mx), e2 = __expf(v2 - mx), e3 = __expf(v3 - mx);
    float sm = e0 + e1 + e2 + e3;
    #pragma unroll
    for (int o = 32; o >= 1; o >>= 1) sm += __shfl_xor(sm, o);
    if (lane == 0) red[4 + wid] = sm;
    __syncthreads();
    const float inv = 1.0f / (red[4] + red[5] + red[6] + red[7]);
    bf16 ov[4] = { f2b(e0 * inv), f2b(e1 * inv), f2b(e2 * inv), f2b(e3 * inv) };
    *(ushort4*)rp = *(const ushort4*)ov;
}

// ---------------- LN over C=256 (wave per row, 4 ch/lane), bf16 in/out ----------------
template<int RELU>
__global__ __launch_bounds__(256) void ln_k(
    const bf16* __restrict__ in, bf16* __restrict__ out,
    const float* __restrict__ g, const float* __restrict__ bta)
{
    const int node = blockIdx.x * 4 + (threadIdx.x >> 6);
    const int lane = threadIdx.x & 63;
    const ushort4 iv = *(const ushort4*)(in + (size_t)node * 256 + lane * 4);
    float v0 = us2f(iv.x), v1 = us2f(iv.y), v2 = us2f(iv.z), v3 = us2f(iv.w);
    float s  = v0 + v1 + v2 + v3;
    float sq = v0*v0 + v1*v1 + v2*v2 + v3*v3;
    #pragma unroll
    for (int o = 32; o >= 1; o >>= 1) { s += __shfl_xor(s, o); sq += __shfl_xor(sq, o); }
    const float mean = s * (1.0f / 256.0f);
    const float var  = sq * (1.0f / 256.0f) - mean * mean;
    const float rs = rsqrtf(var + 1e-5f);
    const float4 gv = *(const float4*)(g + lane * 4);
    const float4 bv = *(const float4*)(bta + lane * 4);
    float y0 = (v0 - mean) * rs * gv.x + bv.x;
    float y1 = (v1 - mean) * rs * gv.y + bv.y;
    float y2 = (v2 - mean) * rs * gv.z + bv.z;
    float y3 = (v3 - mean) * rs * gv.w + bv.w;
    if (RELU) { y0 = fmaxf(y0, 0.f); y1 = fmaxf(y1, 0.f); y2 = fmaxf(y2, 0.f); y3 = fmaxf(y3, 0.f); }
    bf16 ov[4] = { f2b(y0), f2b(y1), f2b(y2), f2b(y3) };
    *(ushort4*)(out + (size_t)node * 256 + lane * 4) = *(const ushort4*)ov;
}

// ---------------- gated blend + LN (wave per row) ----------------
__global__ __launch_bounds__(256) void blend_ln_k(
    const bf16* __restrict__ gate, const bf16* __restrict__ cat1,
    const float* __restrict__ x, bf16* __restrict__ valid,
    const float* __restrict__ g, const float* __restrict__ bta)
{
    const int node = blockIdx.x * 4 + (threadIdx.x >> 6);
    const int lane = threadIdx.x & 63;
    const ushort4 gt4 = *(const ushort4*)(gate + (size_t)node * 256 + lane * 4);
    const ushort4 ao4 = *(const ushort4*)(cat1 + (size_t)node * 512 + lane * 4);
    const float4  xv4 = *(const float4*)(x + (size_t)node * 256 + lane * 4);
    float g0 = us2f(gt4.x), g1 = us2f(gt4.y), g2 = us2f(gt4.z), g3 = us2f(gt4.w);
    float v0 = g0 * us2f(ao4.x) + (1.f - g0) * xv4.x;
    float v1 = g1 * us2f(ao4.y) + (1.f - g1) * xv4.y;
    float v2 = g2 * us2f(ao4.z) + (1.f - g2) * xv4.z;
    float v3 = g3 * us2f(ao4.w) + (1.f - g3) * xv4.w;
    float s  = v0 + v1 + v2 + v3;
    float sq = v0*v0 + v1*v1 + v2*v2 + v3*v3;
    #pragma unroll
    for (int o = 32; o >= 1; o >>= 1) { s += __shfl_xor(s, o); sq += __shfl_xor(sq, o); }
    const float mean = s * (1.0f / 256.0f);
    const float var  = sq * (1.0f / 256.0f) - mean * mean;
    const float rs = rsqrtf(var + 1e-5f);
    const float4 gv = *(const float4*)(g + lane * 4);
    const float4 bv = *(const float4*)(bta + lane * 4);
    bf16 ov[4] = { f2b((v0 - mean) * rs * gv.x + bv.x), f2b((v1 - mean) * rs * gv.y + bv.y),
                   f2b((v2 - mean) * rs * gv.z + bv.z), f2b((v3 - mean) * rs * gv.w + bv.w) };
    *(ushort4*)(valid + (size_t)node * 256 + lane * 4) = *(const ushort4*)ov;
}

// ---------------- confidence layer2 + weighted (wave per node) ----------------
__global__ __launch_bounds__(256) void conf_w_k(
    const bf16* __restrict__ t1, const float* __restrict__ Wc2, const float* __restrict__ bc2,
    const bf16* __restrict__ valid, float* __restrict__ conf, bf16* __restrict__ cat2)
{
    const int node = blockIdx.x * 4 + (threadIdx.x >> 6);
    const int lane = threadIdx.x & 63;
    float a = b2f(t1[(size_t)node * 128 + lane]) * Wc2[lane]
            + b2f(t1[(size_t)node * 128 + 64 + lane]) * Wc2[64 + lane];
    #pragma unroll
    for (int o = 32; o >= 1; o >>= 1) a += __shfl_xor(a, o);
    const float c = 1.0f / (1.0f + __expf(-(a + bc2[0])));
    if (lane == 0) conf[node] = c;
    const ushort4 vv = *(const ushort4*)(valid + (size_t)node * 256 + lane * 4);
    bf16 ov[4] = { f2b(us2f(vv.x) * c), f2b(us2f(vv.y) * c), f2b(us2f(vv.z) * c), f2b(us2f(vv.w) * c) };
    *(ushort4*)(cat2 + (size_t)node * 512 + 256 + lane * 4) = *(const ushort4*)ov;
}

// ---------------- CSR build ----------------
__global__ __launch_bounds__(256) void count2_k(
    const int* __restrict__ dst, const int* __restrict__ et,
    int* __restrict__ deg, int* __restrict__ cnt8)
{
    const int e = blockIdx.x * 256 + threadIdx.x;
    if (e < E_) {
        const int d = dst[e];
        atomicAdd(&deg[d], 1);
        atomicAdd(&cnt8[d * 8 + et[e]], 1);
    }
}

__global__ __launch_bounds__(256) void scan_k(
    const int* __restrict__ deg, int* __restrict__ rowptr, int* __restrict__ cursor)
{
    __shared__ int part[256];
    const int tid = threadIdx.x;
    const int base = tid * 64;
    int s = 0;
    for (int i = 0; i < 64; ++i) s += deg[base + i];
    part[tid] = s; __syncthreads();
    for (int off = 1; off < 256; off <<= 1) {
        int t = (tid >= off) ? part[tid - off] : 0;
        __syncthreads();
        part[tid] += t;
        __syncthreads();
    }
    int run = (tid == 0) ? 0 : part[tid - 1];
    for (int i = 0; i < 64; ++i) {
        rowptr[base + i] = run;
        cursor[base + i] = run;
        run += deg[base + i];
    }
    if (tid == 255) rowptr[BN_] = run;
}

__global__ __launch_bounds__(256) void fill_k(
    const int* __restrict__ src, const int* __restrict__ dst, const int* __restrict__ et,
    int* __restrict__ cursor, int* __restrict__ elist)
{
    const int e = blockIdx.x * 256 + threadIdx.x;
    if (e < E_) {
        const int pos = atomicAdd(&cursor[dst[e]], 1);
        elist[pos] = src[e] | (et[e] << 16);
    }
}

// ---------------- RGCN gather + root + bias + LN2 + relu (wave per node) ----------------
__global__ __launch_bounds__(256) void gather_ln_k(
    const int* __restrict__ rowptr, const int* __restrict__ elist,
    const bf16* __restrict__ h, const int* __restrict__ cnt8,
    const float* __restrict__ brg,
    const float* __restrict__ g, const float* __restrict__ bta,
    bf16* __restrict__ xr)
{
    const int node = blockIdx.x * 4 + (threadIdx.x >> 6);
    const int lane = threadIdx.x & 63;
    const int e0 = rowptr[node], e1 = rowptr[node + 1];
    float invc[8];
    #pragma unroll
    for (int r = 0; r < 8; ++r)
        invc[r] = 1.0f / fmaxf((float)cnt8[node * 8 + r], 1.0f);
    float a0 = 0.f, a1 = 0.f, a2 = 0.f, a3 = 0.f;
    for (int e = e0; e < e1; ++e) {
        const int pe = elist[e];
        const int srcn = pe & 0xffff, rel = pe >> 16;
        const float wgt = invc[rel];
        const ushort4 hv = *(const ushort4*)(h + (size_t)srcn * 2304 + rel * 256 + lane * 4);
        a0 += wgt * us2f(hv.x); a1 += wgt * us2f(hv.y);
        a2 += wgt * us2f(hv.z); a3 += wgt * us2f(hv.w);
    }
    const ushort4 rv = *(const ushort4*)(h + (size_t)node * 2304 + 2048 + lane * 4);
    const float4 bg4 = *(const float4*)(brg + lane * 4);
    const float v0 = a0 + us2f(rv.x) + bg4.x, v1 = a1 + us2f(rv.y) + bg4.y;
    const float v2 = a2 + us2f(rv.z) + bg4.z, v3 = a3 + us2f(rv.w) + bg4.w;
    float s  = v0 + v1 + v2 + v3;
    float sq = v0*v0 + v1*v1 + v2*v2 + v3*v3;
    #pragma unroll
    for (int m = 32; m >= 1; m >>= 1) { s += __shfl_xor(s, m); sq += __shfl_xor(sq, m); }
    const float mean = s * (1.0f / 256.0f);
    const float var  = sq * (1.0f / 256.0f) - mean * mean;
    const float rs = rsqrtf(var + 1e-5f);
    const float4 gv = *(const float4*)(g + lane * 4);
    const float4 bv = *(const float4*)(bta + lane * 4);
    bf16 tb[4] = { f2b(fmaxf((v0 - mean) * rs * gv.x + bv.x, 0.f)),
                   f2b(fmaxf((v1 - mean) * rs * gv.y + bv.y, 0.f)),
                   f2b(fmaxf((v2 - mean) * rs * gv.z + bv.z, 0.f)),
                   f2b(fmaxf((v3 - mean) * rs * gv.w + bv.w, 0.f)) };
    *(ushort4*)(xr + (size_t)node * 256 + lane * 4) = *(const ushort4*)tb;
}

// ---------------- pooling stage 1 ----------------
__global__ __launch_bounds__(256) void pool1_k(
    const bf16* __restrict__ xr, const float* __restrict__ conf, float* __restrict__ partial)
{
    const int b = blockIdx.x, chunk = blockIdx.y, c = threadIdx.x;
    float acc = 0.0f;
    for (int n = 0; n < 64; ++n) {
        const int node = b * 1024 + chunk * 64 + n;
        acc += conf[node] * b2f(xr[(size_t)node * 256 + c]);
    }
    partial[(size_t)(b * 16 + chunk) * 256 + c] = acc;
}

// ---------------- pooling stage 2 + head ----------------
__global__ __launch_bounds__(256) void pool2_k(
    const float* __restrict__ partial, const float* __restrict__ conf,
    const float* __restrict__ Wh, const float* __restrict__ bh, float* __restrict__ out)
{
    const int b = blockIdx.x, tid = threadIdx.x;
    __shared__ float red[256];
    __shared__ float pooled[256];
    float pc = 0.0f;
    for (int ch = 0; ch < 16; ++ch) pc += partial[(size_t)(b * 16 + ch) * 256 + tid];
    float s = conf[b * 1024 + tid] + conf[b * 1024 + 256 + tid]
            + conf[b * 1024 + 512 + tid] + conf[b * 1024 + 768 + tid];
    red[tid] = s; __syncthreads();
    for (int st = 128; st > 0; st >>= 1) { if (tid < st) red[tid] += red[tid + st]; __syncthreads(); }
    const float denom = fmaxf(red[0], 1e-8f);
    pooled[tid] = pc / denom;
    __syncthreads();
    if (tid < NS_) {
        float o = bh[tid];
        for (int c = 0; c < 256; ++c) o += pooled[c] * Wh[c * NS_ + tid];
        out[b * NS_ + tid] = o;
    }
}

extern "C" void kernel_launch(void* const* d_in, const int* in_sizes, int n_in,
                              void* d_out, int out_size, void* d_ws, size_t ws_size,
                              hipStream_t stream) {
    const float* x    = (const float*)d_in[0];
    const int*   ei   = (const int*)d_in[1];
    const int*   et   = (const int*)d_in[2];
    const float* Wq   = (const float*)d_in[3];  const float* bq  = (const float*)d_in[4];
    const float* Wk   = (const float*)d_in[5];  const float* bk  = (const float*)d_in[6];
    const float* Wv   = (const float*)d_in[7];  const float* bv  = (const float*)d_in[8];
    const float* Wg   = (const float*)d_in[9];  const float* bg  = (const float*)d_in[10];
    const float* lag  = (const float*)d_in[11]; const float* lab = (const float*)d_in[12];
    const float* Wc1  = (const float*)d_in[13]; const float* bc1 = (const float*)d_in[14];
    const float* Wc2  = (const float*)d_in[15]; const float* bc2 = (const float*)d_in[16];
    const float* Wm   = (const float*)d_in[17]; const float* bm  = (const float*)d_in[18];
    const float* l1g  = (const float*)d_in[19]; const float* l1b = (const float*)d_in[20];
    const float* Wrel = (const float*)d_in[21]; const float* Wroot = (const float*)d_in[22];
    const float* brg  = (const float*)d_in[23];
    const float* l2g  = (const float*)d_in[24]; const float* l2b = (const float*)d_in[25];
    const float* Wh   = (const float*)d_in[26]; const float* bh  = (const float*)d_in[27];
    const int* esrc = ei;
    const int* edst = ei + E_;

    char* w8 = (char*)d_ws;
    bf16*  qkv   = (bf16*)(w8 + 0);            // [16384,768]
    bf16*  hbuf  = (bf16*)(w8 + 0);            // [16384,2304] (reuses qkv/sP region)
    bf16*  sP    = (bf16*)(w8 + 25165824);     // [16x1024x1024]
    bf16*  cat1  = (bf16*)(w8 + 58720256);     // [aout|xb] ld 512
    bf16*  cat2  = (bf16*)(w8 + 75497472);     // [xb|weighted] ld 512
    bf16*  gate  = (bf16*)(w8 + 92274688);
    bf16*  valid = (bf16*)(w8 + 100663296);
    bf16*  t1    = (bf16*)(w8 + 109051904);
    bf16*  xm    = (bf16*)(w8 + 113246208);
    bf16*  xb    = (bf16*)(w8 + 121634816);
    bf16*  xn    = (bf16*)(w8 + 130023424);
    bf16*  vtb   = (bf16*)(w8 + 138412032);
    bf16*  xr    = (bf16*)(w8 + 146800640);
    float* conf  = (float*)(w8 + 155189248);
    float* part  = (float*)(w8 + 155254784);
    bf16*  WT    = (bf16*)(w8 + 155516928);
    int*  deg    = (int*)(w8 + 157679616);
    int*  cnt8i  = (int*)(w8 + 157745152);
    int*  rowptr = (int*)(w8 + 158269440);
    int*  cursor = (int*)(w8 + 158335232);
    int*  elist  = (int*)(w8 + 158400768);
    bf16* WqkvT = WT;                  // [768,256]
    bf16* WgT   = WT + 196608;         // [256,512]
    bf16* WmT   = WT + 327680;         // [256,512]
    bf16* Wc1T  = WT + 458752;         // [128,256]
    bf16* WBIG  = WT + 491520;         // [2304,256]
    float* outp = (float*)d_out;

    dim3 blk(256);

    // --- prep: weights (1 dispatch), x conversion, CSR build ---
    prep_w_k<<<1056, blk, 0, stream>>>(Wq, Wk, Wv, Wg, Wm, Wc1, Wrel, Wroot, WT);
    cvt_x_k<<<BNC_ / 1024, blk, 0, stream>>>(x, xb, cat1, cat2);
    hipMemsetAsync(deg, 0, 589824, stream);
    count2_k<<<E_ / 256, blk, 0, stream>>>(edst, et, deg, cnt8i);
    scan_k<<<1, blk, 0, stream>>>(deg, rowptr, cursor);
    fill_k<<<E_ / 256, blk, 0, stream>>>(esrc, edst, et, cursor, elist);

    // --- fused QKV projection: qkv[16384,768] ---
    gemm_bf16<0><<<dim3(6, 128, 1), blk, 0, stream>>>(
        xb, 256, 0, WqkvT, 256, 0, qkv, 768, 0, bq, bk, bv, 256);
    vtrans_k<<<dim3(8, 32, 16), blk, 0, stream>>>(qkv, vtb);

    // --- attention: QK^T, softmax, PV (all 128-tile; best measured config) ---
    gemm_bf16<0><<<dim3(8, 8, 16), blk, 0, stream>>>(
        qkv, 768, 786432, qkv + 256, 768, 786432, sP, 1024, 1048576, nullptr, nullptr, nullptr, 256);
    softmax_k<<<BN_, blk, 0, stream>>>(sP);
    gemm_bf16<0><<<dim3(2, 8, 16), blk, 0, stream>>>(
        sP, 1024, 1048576, vtb, 1024, 262144, cat1, 512, 524288, nullptr, nullptr, nullptr, 1024);

    // --- gate, blend+LN ---
    gemm_bf16<2><<<dim3(2, 128, 1), blk, 0, stream>>>(
        cat1, 512, 0, WgT, 512, 0, gate, 256, 0, bg, nullptr, nullptr, 512);
    blend_ln_k<<<BN_ / 4, blk, 0, stream>>>(gate, cat1, x, valid, lag, lab);

    // --- confidence + weighted ---
    gemm_bf16<1><<<dim3(1, 128, 1), blk, 0, stream>>>(
        valid, 256, 0, Wc1T, 256, 0, t1, 128, 0, bc1, nullptr, nullptr, 256);
    conf_w_k<<<BN_ / 4, blk, 0, stream>>>(t1, Wc2, bc2, valid, conf, cat2);

    // --- mixer + LN1 ---
    gemm_bf16<1><<<dim3(2, 128, 1), blk, 0, stream>>>(
        cat2, 512, 0, WmT, 512, 0, xm, 256, 0, bm, nullptr, nullptr, 512);
    ln_k<0><<<BN_ / 4, blk, 0, stream>>>(xm, xn, l1g, l1b);

    // --- RGCN: one GEMM (128-tile, 2304 blocks, XCD-swizzled), gather + LN2 ---
    gemm_bf16<0><<<dim3(18, 128, 1), blk, 0, stream>>>(
        xn, 256, 0, WBIG, 256, 0, hbuf, 2304, 0, nullptr, nullptr, nullptr, 256);
    gather_ln_k<<<BN_ / 4, blk, 0, stream>>>(rowptr, elist, hbuf, cnt8i, brg, l2g, l2b, xr);

    // --- pool + head ---
    pool1_k<<<dim3(B_, 16), blk, 0, stream>>>(xr, conf, part);
    pool2_k<<<B_, blk, 0, stream>>>(part, conf, Wh, bh, outp);
}

// Round 11
// 263.814 us; speedup vs baseline: 1.4977x; 1.0608x over previous
//
#include <hip/hip_runtime.h>
#include <hip/hip_bf16.h>

#define B_ 16
#define N_ 1024
#define C_ 256
#define R_ 8
#define E_ 262144
#define NS_ 32
#define BN_ (B_*N_)
#define BNC_ (BN_*C_)

typedef __hip_bfloat16 bf16;
typedef __attribute__((ext_vector_type(4))) float f32x4;
typedef __attribute__((ext_vector_type(8))) short bf16x8;

__device__ __forceinline__ float b2f(bf16 x) { return __bfloat162float(x); }
__device__ __forceinline__ bf16  f2b(float x) { return __float2bfloat16(x); }
__device__ __forceinline__ float us2f(unsigned short u) { return __uint_as_float((unsigned)u << 16); }

// async global->LDS, 16B per lane (wave-uniform LDS base + lane*16 implicit)
__device__ __forceinline__ void gload16(const void* g, void* l) {
    auto gp = (const __attribute__((address_space(1))) void*)(unsigned long long)g;
    auto lp = (__attribute__((address_space(3))) void*)(unsigned)(unsigned long long)l;
    __builtin_amdgcn_global_load_lds(gp, lp, 16, 0, 0);
}

// ---------------- bf16 MFMA GEMM (128x128 tile): C = act(A @ B^T + bias) ----------------
// Depth-2 pipeline, counted vmcnt(4); XOR slot swizzle both sides (rule #21).
// T1 XCD-aware block swizzle (bijective when nwg % 8 == 0).
template<int ACT>
__global__ __launch_bounds__(256) void gemm_bf16(
    const bf16* __restrict__ A, int lda, long long sA,
    const bf16* __restrict__ Bm, int ldb, long long sB,
    bf16* __restrict__ Cc, int ldc, long long sC,
    const float* __restrict__ bias, const float* __restrict__ bias2,
    const float* __restrict__ bias3, int K)
{
    __shared__ short sbuf[16384];        // 32 KB
    const int tid = threadIdx.x;
    const int lane = tid & 63, w = tid >> 6;
    const int wr = w >> 1, wc = w & 1;

    const int gx = gridDim.x;
    const int nwg = gx * gridDim.y;
    int id = blockIdx.y * gx + blockIdx.x;
    if ((nwg & 7) == 0) { const int cpx = nwg >> 3; id = (id & 7) * cpx + (id >> 3); }
    const int bm = (id / gx) * 128, bn = (id % gx) * 128;

    const bf16* Ab = A + (size_t)blockIdx.z * sA;
    const bf16* Bb = Bm + (size_t)blockIdx.z * sB;
    bf16* Cb = Cc + (size_t)blockIdx.z * sC;

    const int rg = lane >> 2;
    const int kswz = ((lane & 3) ^ ((rg >> 1) & 3)) * 8;

    f32x4 acc[4][4];
    const f32x4 zz = {0.f, 0.f, 0.f, 0.f};
    #pragma unroll
    for (int i = 0; i < 4; ++i)
        #pragma unroll
        for (int j = 0; j < 4; ++j) acc[i][j] = zz;

    const int fr = lane & 15;
    const int fm = lane >> 4;
    const int fslot = (fm ^ ((fr >> 1) & 3)) * 8;

    const int NI = K >> 5;

#define STAGE_AB(bi, kk) do {                                                          \
    _Pragma("unroll")                                                                  \
    for (int t_ = 0; t_ < 2; ++t_) {                                                   \
        gload16(Ab + (size_t)(bm + t_*64 + w*16 + rg) * lda + (kk) + kswz,             \
                sbuf + (bi)*4096 + t_*2048 + w*512);                                   \
        gload16(Bb + (size_t)(bn + t_*64 + w*16 + rg) * ldb + (kk) + kswz,             \
                sbuf + 8192 + (bi)*4096 + t_*2048 + w*512);                            \
    } } while (0)

    STAGE_AB(0, 0);
    if (NI > 1) STAGE_AB(1, 32);

    for (int i = 0; i < NI; ++i) {
        const int cur = i & 1;
        if (i + 1 < NI) asm volatile("s_waitcnt vmcnt(4)" ::: "memory");
        else            asm volatile("s_waitcnt vmcnt(0)" ::: "memory");
        __builtin_amdgcn_s_barrier();
        __builtin_amdgcn_sched_barrier(0);

        bf16x8 af[4], bfr[4];
        const short* Ac = sbuf + cur * 4096;
        const short* Bc = sbuf + 8192 + cur * 4096;
        #pragma unroll
        for (int ii = 0; ii < 4; ++ii)
            af[ii] = *(const bf16x8*)&Ac[(wr*64 + ii*16 + fr)*32 + fslot];
        #pragma unroll
        for (int jj = 0; jj < 4; ++jj)
            bfr[jj] = *(const bf16x8*)&Bc[(wc*64 + jj*16 + fr)*32 + fslot];

        asm volatile("s_waitcnt lgkmcnt(0)" ::: "memory");
        __builtin_amdgcn_s_barrier();
        __builtin_amdgcn_sched_barrier(0);
        if (i + 2 < NI) STAGE_AB(cur, (i + 2) * 32);

        #pragma unroll
        for (int ii = 0; ii < 4; ++ii)
            #pragma unroll
            for (int jj = 0; jj < 4; ++jj)
                acc[ii][jj] = __builtin_amdgcn_mfma_f32_16x16x32_bf16(af[ii], bfr[jj], acc[ii][jj], 0, 0, 0);
    }
#undef STAGE_AB

    __syncthreads();
    const int er = (lane >> 4) * 4, ec = lane & 15;
    #pragma unroll
    for (int half = 0; half < 2; ++half) {
        if (wr == half) {
            #pragma unroll
            for (int j = 0; j < 4; ++j) {
                const int col = bn + wc*64 + j*16 + ec;
                float bvv = 0.0f;
                if (bias) {
                    const int seg = col >> 8;
                    const float* bp = (seg == 0) ? bias : (seg == 1 ? bias2 : bias3);
                    bvv = bp[col & 255];
                }
                #pragma unroll
                for (int i = 0; i < 4; ++i) {
                    #pragma unroll
                    for (int p = 0; p < 4; ++p) {
                        float val = acc[i][j][p] + bvv;
                        if (ACT == 1) val = fmaxf(val, 0.0f);
                        if (ACT == 2) val = 1.0f / (1.0f + __expf(-val));
                        *(bf16*)&sbuf[(i*16 + er + p)*136 + wc*64 + j*16 + ec] = f2b(val);
                    }
                }
            }
        }
        __syncthreads();
        #pragma unroll
        for (int it = 0; it < 4; ++it) {
            const int ch = tid + it*256;
            const int row = ch >> 4, cp = (ch & 15) * 8;
            *(bf16x8*)&Cb[(size_t)(bm + half*64 + row) * ldc + bn + cp] =
                *(const bf16x8*)&sbuf[row*136 + cp];
        }
        __syncthreads();
    }
}

// ---------------- bf16 MFMA GEMM (64x64 tile, depth-4 pipeline) ----------------
// For the serial latency-bound chain (gate/conf/mixer): small grids need both
// more blocks/CU AND deeper prefetch. 4 LDS buffers (32 KB), vmcnt ladder
// 6/4/2/0 keeps 3 tiles in flight. Same XOR swizzle both sides; XCD swizzle.
template<int ACT>
__global__ __launch_bounds__(256) void gemm64_bf16(
    const bf16* __restrict__ A, int lda, long long sA,
    const bf16* __restrict__ Bm, int ldb, long long sB,
    bf16* __restrict__ Cc, int ldc, long long sC,
    const float* __restrict__ bias, int K)
{
    __shared__ short sbuf[16384];        // 32 KB: A0..A3 @ bi*2048, B0..B3 @ 8192+bi*2048
    const int tid = threadIdx.x;
    const int lane = tid & 63, w = tid >> 6;
    const int wr = w >> 1, wc = w & 1;   // 2x2 quadrants of 32x32

    const int gx = gridDim.x;
    const int nwg = gx * gridDim.y;
    int id = blockIdx.y * gx + blockIdx.x;
    if ((nwg & 7) == 0) { const int cpx = nwg >> 3; id = (id & 7) * cpx + (id >> 3); }
    const int bm = (id / gx) * 64, bn = (id % gx) * 64;

    const bf16* Ab = A + (size_t)blockIdx.z * sA;
    const bf16* Bb = Bm + (size_t)blockIdx.z * sB;
    bf16* Cb = Cc + (size_t)blockIdx.z * sC;

    const int rg = lane >> 2;
    const int kswz = ((lane & 3) ^ ((rg >> 1) & 3)) * 8;

    f32x4 acc[2][2];
    const f32x4 zz = {0.f, 0.f, 0.f, 0.f};
    #pragma unroll
    for (int i = 0; i < 2; ++i)
        #pragma unroll
        for (int j = 0; j < 2; ++j) acc[i][j] = zz;

    const int fr = lane & 15;
    const int fm = lane >> 4;
    const int fslot = (fm ^ ((fr >> 1) & 3)) * 8;

    const int NI = K >> 5;

#define STAGE64(bi, kk) do {                                                           \
    gload16(Ab + (size_t)(bm + w*16 + rg) * lda + (kk) + kswz,                         \
            sbuf + (bi)*2048 + w*512);                                                 \
    gload16(Bb + (size_t)(bn + w*16 + rg) * ldb + (kk) + kswz,                         \
            sbuf + 8192 + (bi)*2048 + w*512);                                          \
    } while (0)

    STAGE64(0, 0);
    if (NI > 1) STAGE64(1, 32);
    if (NI > 2) STAGE64(2, 64);
    if (NI > 3) STAGE64(3, 96);

    for (int i = 0; i < NI; ++i) {
        const int cur = i & 3;
        if (i + 3 < NI)      asm volatile("s_waitcnt vmcnt(6)" ::: "memory");
        else if (i + 2 < NI) asm volatile("s_waitcnt vmcnt(4)" ::: "memory");
        else if (i + 1 < NI) asm volatile("s_waitcnt vmcnt(2)" ::: "memory");
        else                 asm volatile("s_waitcnt vmcnt(0)" ::: "memory");
        __builtin_amdgcn_s_barrier();
        __builtin_amdgcn_sched_barrier(0);

        bf16x8 af[2], bfr[2];
        const short* Ac = sbuf + cur * 2048;
        const short* Bc = sbuf + 8192 + cur * 2048;
        #pragma unroll
        for (int ii = 0; ii < 2; ++ii)
            af[ii] = *(const bf16x8*)&Ac[(wr*32 + ii*16 + fr)*32 + fslot];
        #pragma unroll
        for (int jj = 0; jj < 2; ++jj)
            bfr[jj] = *(const bf16x8*)&Bc[(wc*32 + jj*16 + fr)*32 + fslot];

        asm volatile("s_waitcnt lgkmcnt(0)" ::: "memory");
        __builtin_amdgcn_s_barrier();
        __builtin_amdgcn_sched_barrier(0);
        if (i + 4 < NI) STAGE64(cur, (i + 4) * 32);

        #pragma unroll
        for (int ii = 0; ii < 2; ++ii)
            #pragma unroll
            for (int jj = 0; jj < 2; ++jj)
                acc[ii][jj] = __builtin_amdgcn_mfma_f32_16x16x32_bf16(af[ii], bfr[jj], acc[ii][jj], 0, 0, 0);
    }
#undef STAGE64

    // epilogue: 4 waves write distinct 32x32 quadrants into 64x72 LDS, then 16B stores
    __syncthreads();
    const int er = (lane >> 4) * 4, ec = lane & 15;
    #pragma unroll
    for (int j = 0; j < 2; ++j) {
        const int col = bn + wc*32 + j*16 + ec;
        const float bvv = bias ? bias[col & 255] : 0.0f;
        #pragma unroll
        for (int i = 0; i < 2; ++i) {
            #pragma unroll
            for (int p = 0; p < 4; ++p) {
                float val = acc[i][j][p] + bvv;
                if (ACT == 1) val = fmaxf(val, 0.0f);
                if (ACT == 2) val = 1.0f / (1.0f + __expf(-val));
                *(bf16*)&sbuf[(wr*32 + i*16 + er + p)*72 + wc*32 + j*16 + ec] = f2b(val);
            }
        }
    }
    __syncthreads();
    #pragma unroll
    for (int it = 0; it < 2; ++it) {
        const int ch = tid + it*256;
        const int row = ch >> 3, cp = (ch & 7) * 8;
        *(bf16x8*)&Cb[(size_t)(bm + row) * ldc + bn + cp] =
            *(const bf16x8*)&sbuf[row*72 + cp];
    }
}

// ---------------- all weight transposes fp32[K,Nn] -> bf16[Nn,K], one dispatch ----------------
__global__ __launch_bounds__(256) void prep_w_k(
    const float* __restrict__ Wq, const float* __restrict__ Wk, const float* __restrict__ Wv,
    const float* __restrict__ Wg, const float* __restrict__ Wm, const float* __restrict__ Wc1,
    const float* __restrict__ Wrel, const float* __restrict__ Wroot, bf16* __restrict__ WT)
{
    int t = blockIdx.x;
    const float* in; bf16* out; int K, Nn;
    if (t < 192)      { int wsel = t >> 6; t &= 63;
                        in = wsel == 0 ? Wq : (wsel == 1 ? Wk : Wv);
                        out = WT + wsel*65536; K = 256; Nn = 256; }
    else if (t < 320) { t -= 192; in = Wg;  out = WT + 196608; K = 512; Nn = 256; }
    else if (t < 448) { t -= 320; in = Wm;  out = WT + 327680; K = 512; Nn = 256; }
    else if (t < 480) { t -= 448; in = Wc1; out = WT + 458752; K = 256; Nn = 128; }
    else if (t < 992) { t -= 480; int r = t >> 6; t &= 63;
                        in = Wrel + (size_t)r*65536; out = WT + 491520 + r*65536; K = 256; Nn = 256; }
    else              { t -= 992; in = Wroot; out = WT + 491520 + 524288; K = 256; Nn = 256; }
    const int tpr = Nn >> 5;
    const int n0 = (t % tpr) * 32, k0 = (t / tpr) * 32;
    __shared__ float tile[32][33];
    const int tx = threadIdx.x & 31, ty = threadIdx.x >> 5;
    #pragma unroll
    for (int i = 0; i < 4; ++i) {
        int r = ty + i*8;
        tile[r][tx] = in[(size_t)(k0 + r) * Nn + n0 + tx];
    }
    __syncthreads();
    #pragma unroll
    for (int i = 0; i < 4; ++i) {
        int r = ty + i*8;
        out[(size_t)(n0 + r) * K + k0 + tx] = f2b(tile[tx][r]);
    }
}

// ---------------- V^T: qkv V-part [1024,256] (ld 768) -> vtb [256,1024] per batch ----------------
__global__ __launch_bounds__(256) void vtrans_k(
    const bf16* __restrict__ in, bf16* __restrict__ out)
{
    __shared__ float tile[32][33];
    in  += (size_t)blockIdx.z * 786432 + 512;
    out += (size_t)blockIdx.z * 262144;
    const int n0 = blockIdx.x * 32, k0 = blockIdx.y * 32;
    const int tx = threadIdx.x & 31, ty = threadIdx.x >> 5;
    #pragma unroll
    for (int i = 0; i < 4; ++i) {
        int r = ty + i*8;
        tile[r][tx] = b2f(in[(size_t)(k0 + r) * 768 + n0 + tx]);
    }
    __syncthreads();
    #pragma unroll
    for (int i = 0; i < 4; ++i) {
        int r = ty + i*8;
        out[(size_t)(n0 + r) * 1024 + k0 + tx] = f2b(tile[tx][r]);
    }
}

// ---------------- x fp32 -> bf16 (xb, cat1 right half, cat2 left half), 4 el/thread ----------------
__global__ __launch_bounds__(256) void cvt_x_k(const float* __restrict__ x,
    bf16* __restrict__ xb, bf16* __restrict__ cat1, bf16* __restrict__ cat2)
{
    const int i4 = (blockIdx.x * 256 + threadIdx.x) * 4;
    const float4 xv = *(const float4*)(x + i4);
    bf16 bv[4] = { f2b(xv.x), f2b(xv.y), f2b(xv.z), f2b(xv.w) };
    const ushort4 pack = *(const ushort4*)bv;
    const int row = i4 >> 8, col = i4 & 255;
    *(ushort4*)(xb + i4) = pack;
    *(ushort4*)(cat1 + (size_t)row * 512 + 256 + col) = pack;
    *(ushort4*)(cat2 + (size_t)row * 512 + col) = pack;
}

// ---------------- row softmax over 1024 bf16 scores in place (pre-scale 1/16) ----------------
__global__ __launch_bounds__(256) void softmax_k(bf16* __restrict__ s)
{
    const int row = blockIdx.x, tid = threadIdx.x;
    const int lane = tid & 63, wid = tid >> 6;
    bf16* rp = s + (size_t)row * 1024 + tid * 4;
    __shared__ float red[8];
    const ushort4 sv = *(const ushort4*)rp;
    float v0 = us2f(sv.x) * 0.0625f, v1 = us2f(sv.y) * 0.0625f;
    float v2 = us2f(sv.z) * 0.0625f, v3 = us2f(sv.w) * 0.0625f;
    float m = fmaxf(fmaxf(v0, v1), fmaxf(v2, v3));
    #pragma unroll
    for (int o = 32; o >= 1; o >>= 1) m = fmaxf(m, __shfl_xor(m, o));
    if (lane == 0) red[wid] = m;
    __syncthreads();
    const float mx = fmaxf(fmaxf(red[0], red[1]), fmaxf(red[2], red[3]));
    float e0 = __expf(v0 - mx), e1 = __expf(v1 - mx), e2 = __expf(v2 - mx), e3 = __expf(v3 - mx);
    float sm = e0 + e1 + e2 + e3;
    #pragma unroll
    for (int o = 32; o >= 1; o >>= 1) sm += __shfl_xor(sm, o);
    if (lane == 0) red[4 + wid] = sm;
    __syncthreads();
    const float inv = 1.0f / (red[4] + red[5] + red[6] + red[7]);
    bf16 ov[4] = { f2b(e0 * inv), f2b(e1 * inv), f2b(e2 * inv), f2b(e3 * inv) };
    *(ushort4*)rp = *(const ushort4*)ov;
}

// ---------------- LN over C=256 (wave per row, 4 ch/lane), bf16 in/out ----------------
template<int RELU>
__global__ __launch_bounds__(256) void ln_k(
    const bf16* __restrict__ in, bf16* __restrict__ out,
    const float* __restrict__ g, const float* __restrict__ bta)
{
    const int node = blockIdx.x * 4 + (threadIdx.x >> 6);
    const int lane = threadIdx.x & 63;
    const ushort4 iv = *(const ushort4*)(in + (size_t)node * 256 + lane * 4);
    float v0 = us2f(iv.x), v1 = us2f(iv.y), v2 = us2f(iv.z), v3 = us2f(iv.w);
    float s  = v0 + v1 + v2 + v3;
    float sq = v0*v0 + v1*v1 + v2*v2 + v3*v3;
    #pragma unroll
    for (int o = 32; o >= 1; o >>= 1) { s += __shfl_xor(s, o); sq += __shfl_xor(sq, o); }
    const float mean = s * (1.0f / 256.0f);
    const float var  = sq * (1.0f / 256.0f) - mean * mean;
    const float rs = rsqrtf(var + 1e-5f);
    const float4 gv = *(const float4*)(g + lane * 4);
    const float4 bv = *(const float4*)(bta + lane * 4);
    float y0 = (v0 - mean) * rs * gv.x + bv.x;
    float y1 = (v1 - mean) * rs * gv.y + bv.y;
    float y2 = (v2 - mean) * rs * gv.z + bv.z;
    float y3 = (v3 - mean) * rs * gv.w + bv.w;
    if (RELU) { y0 = fmaxf(y0, 0.f); y1 = fmaxf(y1, 0.f); y2 = fmaxf(y2, 0.f); y3 = fmaxf(y3, 0.f); }
    bf16 ov[4] = { f2b(y0), f2b(y1), f2b(y2), f2b(y3) };
    *(ushort4*)(out + (size_t)node * 256 + lane * 4) = *(const ushort4*)ov;
}

// ---------------- gated blend + LN (wave per row) ----------------
__global__ __launch_bounds__(256) void blend_ln_k(
    const bf16* __restrict__ gate, const bf16* __restrict__ cat1,
    const float* __restrict__ x, bf16* __restrict__ valid,
    const float* __restrict__ g, const float* __restrict__ bta)
{
    const int node = blockIdx.x * 4 + (threadIdx.x >> 6);
    const int lane = threadIdx.x & 63;
    const ushort4 gt4 = *(const ushort4*)(gate + (size_t)node * 256 + lane * 4);
    const ushort4 ao4 = *(const ushort4*)(cat1 + (size_t)node * 512 + lane * 4);
    const float4  xv4 = *(const float4*)(x + (size_t)node * 256 + lane * 4);
    float g0 = us2f(gt4.x), g1 = us2f(gt4.y), g2 = us2f(gt4.z), g3 = us2f(gt4.w);
    float v0 = g0 * us2f(ao4.x) + (1.f - g0) * xv4.x;
    float v1 = g1 * us2f(ao4.y) + (1.f - g1) * xv4.y;
    float v2 = g2 * us2f(ao4.z) + (1.f - g2) * xv4.z;
    float v3 = g3 * us2f(ao4.w) + (1.f - g3) * xv4.w;
    float s  = v0 + v1 + v2 + v3;
    float sq = v0*v0 + v1*v1 + v2*v2 + v3*v3;
    #pragma unroll
    for (int o = 32; o >= 1; o >>= 1) { s += __shfl_xor(s, o); sq += __shfl_xor(sq, o); }
    const float mean = s * (1.0f / 256.0f);
    const float var  = sq * (1.0f / 256.0f) - mean * mean;
    const float rs = rsqrtf(var + 1e-5f);
    const float4 gv = *(const float4*)(g + lane * 4);
    const float4 bv = *(const float4*)(bta + lane * 4);
    bf16 ov[4] = { f2b((v0 - mean) * rs * gv.x + bv.x), f2b((v1 - mean) * rs * gv.y + bv.y),
                   f2b((v2 - mean) * rs * gv.z + bv.z), f2b((v3 - mean) * rs * gv.w + bv.w) };
    *(ushort4*)(valid + (size_t)node * 256 + lane * 4) = *(const ushort4*)ov;
}

// ---------------- confidence layer2 + weighted (wave per node) ----------------
__global__ __launch_bounds__(256) void conf_w_k(
    const bf16* __restrict__ t1, const float* __restrict__ Wc2, const float* __restrict__ bc2,
    const bf16* __restrict__ valid, float* __restrict__ conf, bf16* __restrict__ cat2)
{
    const int node = blockIdx.x * 4 + (threadIdx.x >> 6);
    const int lane = threadIdx.x & 63;
    float a = b2f(t1[(size_t)node * 128 + lane]) * Wc2[lane]
            + b2f(t1[(size_t)node * 128 + 64 + lane]) * Wc2[64 + lane];
    #pragma unroll
    for (int o = 32; o >= 1; o >>= 1) a += __shfl_xor(a, o);
    const float c = 1.0f / (1.0f + __expf(-(a + bc2[0])));
    if (lane == 0) conf[node] = c;
    const ushort4 vv = *(const ushort4*)(valid + (size_t)node * 256 + lane * 4);
    bf16 ov[4] = { f2b(us2f(vv.x) * c), f2b(us2f(vv.y) * c), f2b(us2f(vv.z) * c), f2b(us2f(vv.w) * c) };
    *(ushort4*)(cat2 + (size_t)node * 512 + 256 + lane * 4) = *(const ushort4*)ov;
}

// ---------------- CSR build ----------------
__global__ __launch_bounds__(256) void count2_k(
    const int* __restrict__ dst, const int* __restrict__ et,
    int* __restrict__ deg, int* __restrict__ cnt8)
{
    const int e = blockIdx.x * 256 + threadIdx.x;
    if (e < E_) {
        const int d = dst[e];
        atomicAdd(&deg[d], 1);
        atomicAdd(&cnt8[d * 8 + et[e]], 1);
    }
}

__global__ __launch_bounds__(256) void scan_k(
    const int* __restrict__ deg, int* __restrict__ rowptr, int* __restrict__ cursor)
{
    __shared__ int part[256];
    const int tid = threadIdx.x;
    const int base = tid * 64;
    int s = 0;
    for (int i = 0; i < 64; ++i) s += deg[base + i];
    part[tid] = s; __syncthreads();
    for (int off = 1; off < 256; off <<= 1) {
        int t = (tid >= off) ? part[tid - off] : 0;
        __syncthreads();
        part[tid] += t;
        __syncthreads();
    }
    int run = (tid == 0) ? 0 : part[tid - 1];
    for (int i = 0; i < 64; ++i) {
        rowptr[base + i] = run;
        cursor[base + i] = run;
        run += deg[base + i];
    }
    if (tid == 255) rowptr[BN_] = run;
}

__global__ __launch_bounds__(256) void fill_k(
    const int* __restrict__ src, const int* __restrict__ dst, const int* __restrict__ et,
    int* __restrict__ cursor, int* __restrict__ elist)
{
    const int e = blockIdx.x * 256 + threadIdx.x;
    if (e < E_) {
        const int pos = atomicAdd(&cursor[dst[e]], 1);
        elist[pos] = src[e] | (et[e] << 16);
    }
}

// ---------------- RGCN gather + root + bias + LN2 + relu (wave per node) ----------------
// 2-edge unrolled: two independent h-row loads in flight per wave.
__global__ __launch_bounds__(256) void gather_ln_k(
    const int* __restrict__ rowptr, const int* __restrict__ elist,
    const bf16* __restrict__ h, const int* __restrict__ cnt8,
    const float* __restrict__ brg,
    const float* __restrict__ g, const float* __restrict__ bta,
    bf16* __restrict__ xr)
{
    const int node = blockIdx.x * 4 + (threadIdx.x >> 6);
    const int lane = threadIdx.x & 63;
    const int e0 = rowptr[node], e1 = rowptr[node + 1];
    float invc[8];
    #pragma unroll
    for (int r = 0; r < 8; ++r)
        invc[r] = 1.0f / fmaxf((float)cnt8[node * 8 + r], 1.0f);
    float a0 = 0.f, a1 = 0.f, a2 = 0.f, a3 = 0.f;
    int e = e0;
    for (; e + 1 < e1; e += 2) {
        const int pe0 = elist[e], pe1 = elist[e + 1];
        const float w0 = invc[pe0 >> 16], w1 = invc[pe1 >> 16];
        const ushort4 hv0 = *(const ushort4*)(h + (size_t)(pe0 & 0xffff) * 2304 + (pe0 >> 16) * 256 + lane * 4);
        const ushort4 hv1 = *(const ushort4*)(h + (size_t)(pe1 & 0xffff) * 2304 + (pe1 >> 16) * 256 + lane * 4);
        a0 += w0 * us2f(hv0.x) + w1 * us2f(hv1.x);
        a1 += w0 * us2f(hv0.y) + w1 * us2f(hv1.y);
        a2 += w0 * us2f(hv0.z) + w1 * us2f(hv1.z);
        a3 += w0 * us2f(hv0.w) + w1 * us2f(hv1.w);
    }
    if (e < e1) {
        const int pe = elist[e];
        const float wgt = invc[pe >> 16];
        const ushort4 hv = *(const ushort4*)(h + (size_t)(pe & 0xffff) * 2304 + (pe >> 16) * 256 + lane * 4);
        a0 += wgt * us2f(hv.x); a1 += wgt * us2f(hv.y);
        a2 += wgt * us2f(hv.z); a3 += wgt * us2f(hv.w);
    }
    const ushort4 rv = *(const ushort4*)(h + (size_t)node * 2304 + 2048 + lane * 4);
    const float4 bg4 = *(const float4*)(brg + lane * 4);
    const float v0 = a0 + us2f(rv.x) + bg4.x, v1 = a1 + us2f(rv.y) + bg4.y;
    const float v2 = a2 + us2f(rv.z) + bg4.z, v3 = a3 + us2f(rv.w) + bg4.w;
    float s  = v0 + v1 + v2 + v3;
    float sq = v0*v0 + v1*v1 + v2*v2 + v3*v3;
    #pragma unroll
    for (int m = 32; m >= 1; m >>= 1) { s += __shfl_xor(s, m); sq += __shfl_xor(sq, m); }
    const float mean = s * (1.0f / 256.0f);
    const float var  = sq * (1.0f / 256.0f) - mean * mean;
    const float rs = rsqrtf(var + 1e-5f);
    const float4 gv = *(const float4*)(g + lane * 4);
    const float4 bv = *(const float4*)(bta + lane * 4);
    bf16 tb[4] = { f2b(fmaxf((v0 - mean) * rs * gv.x + bv.x, 0.f)),
                   f2b(fmaxf((v1 - mean) * rs * gv.y + bv.y, 0.f)),
                   f2b(fmaxf((v2 - mean) * rs * gv.z + bv.z, 0.f)),
                   f2b(fmaxf((v3 - mean) * rs * gv.w + bv.w, 0.f)) };
    *(ushort4*)(xr + (size_t)node * 256 + lane * 4) = *(const ushort4*)tb;
}

// ---------------- pooling stage 1 ----------------
__global__ __launch_bounds__(256) void pool1_k(
    const bf16* __restrict__ xr, const float* __restrict__ conf, float* __restrict__ partial)
{
    const int b = blockIdx.x, chunk = blockIdx.y, c = threadIdx.x;
    float acc = 0.0f;
    for (int n = 0; n < 64; ++n) {
        const int node = b * 1024 + chunk * 64 + n;
        acc += conf[node] * b2f(xr[(size_t)node * 256 + c]);
    }
    partial[(size_t)(b * 16 + chunk) * 256 + c] = acc;
}

// ---------------- pooling stage 2 + head ----------------
__global__ __launch_bounds__(256) void pool2_k(
    const float* __restrict__ partial, const float* __restrict__ conf,
    const float* __restrict__ Wh, const float* __restrict__ bh, float* __restrict__ out)
{
    const int b = blockIdx.x, tid = threadIdx.x;
    __shared__ float red[256];
    __shared__ float pooled[256];
    float pc = 0.0f;
    for (int ch = 0; ch < 16; ++ch) pc += partial[(size_t)(b * 16 + ch) * 256 + tid];
    float s = conf[b * 1024 + tid] + conf[b * 1024 + 256 + tid]
            + conf[b * 1024 + 512 + tid] + conf[b * 1024 + 768 + tid];
    red[tid] = s; __syncthreads();
    for (int st = 128; st > 0; st >>= 1) { if (tid < st) red[tid] += red[tid + st]; __syncthreads(); }
    const float denom = fmaxf(red[0], 1e-8f);
    pooled[tid] = pc / denom;
    __syncthreads();
    if (tid < NS_) {
        float o = bh[tid];
        for (int c = 0; c < 256; ++c) o += pooled[c] * Wh[c * NS_ + tid];
        out[b * NS_ + tid] = o;
    }
}

extern "C" void kernel_launch(void* const* d_in, const int* in_sizes, int n_in,
                              void* d_out, int out_size, void* d_ws, size_t ws_size,
                              hipStream_t stream) {
    const float* x    = (const float*)d_in[0];
    const int*   ei   = (const int*)d_in[1];
    const int*   et   = (const int*)d_in[2];
    const float* Wq   = (const float*)d_in[3];  const float* bq  = (const float*)d_in[4];
    const float* Wk   = (const float*)d_in[5];  const float* bk  = (const float*)d_in[6];
    const float* Wv   = (const float*)d_in[7];  const float* bv  = (const float*)d_in[8];
    const float* Wg   = (const float*)d_in[9];  const float* bg  = (const float*)d_in[10];
    const float* lag  = (const float*)d_in[11]; const float* lab = (const float*)d_in[12];
    const float* Wc1  = (const float*)d_in[13]; const float* bc1 = (const float*)d_in[14];
    const float* Wc2  = (const float*)d_in[15]; const float* bc2 = (const float*)d_in[16];
    const float* Wm   = (const float*)d_in[17]; const float* bm  = (const float*)d_in[18];
    const float* l1g  = (const float*)d_in[19]; const float* l1b = (const float*)d_in[20];
    const float* Wrel = (const float*)d_in[21]; const float* Wroot = (const float*)d_in[22];
    const float* brg  = (const float*)d_in[23];
    const float* l2g  = (const float*)d_in[24]; const float* l2b = (const float*)d_in[25];
    const float* Wh   = (const float*)d_in[26]; const float* bh  = (const float*)d_in[27];
    const int* esrc = ei;
    const int* edst = ei + E_;

    char* w8 = (char*)d_ws;
    bf16*  qkv   = (bf16*)(w8 + 0);            // [16384,768]
    bf16*  hbuf  = (bf16*)(w8 + 0);            // [16384,2304] (reuses qkv/sP region)
    bf16*  sP    = (bf16*)(w8 + 25165824);     // [16x1024x1024]
    bf16*  cat1  = (bf16*)(w8 + 58720256);     // [aout|xb] ld 512
    bf16*  cat2  = (bf16*)(w8 + 75497472);     // [xb|weighted] ld 512
    bf16*  gate  = (bf16*)(w8 + 92274688);
    bf16*  valid = (bf16*)(w8 + 100663296);
    bf16*  t1    = (bf16*)(w8 + 109051904);
    bf16*  xm    = (bf16*)(w8 + 113246208);
    bf16*  xb    = (bf16*)(w8 + 121634816);
    bf16*  xn    = (bf16*)(w8 + 130023424);
    bf16*  vtb   = (bf16*)(w8 + 138412032);
    bf16*  xr    = (bf16*)(w8 + 146800640);
    float* conf  = (float*)(w8 + 155189248);
    float* part  = (float*)(w8 + 155254784);
    bf16*  WT    = (bf16*)(w8 + 155516928);
    int*  deg    = (int*)(w8 + 157679616);
    int*  cnt8i  = (int*)(w8 + 157745152);
    int*  rowptr = (int*)(w8 + 158269440);
    int*  cursor = (int*)(w8 + 158335232);
    int*  elist  = (int*)(w8 + 158400768);
    bf16* WqkvT = WT;                  // [768,256]
    bf16* WgT   = WT + 196608;         // [256,512]
    bf16* WmT   = WT + 327680;         // [256,512]
    bf16* Wc1T  = WT + 458752;         // [128,256]
    bf16* WBIG  = WT + 491520;         // [2304,256]
    float* outp = (float*)d_out;

    dim3 blk(256);

    // --- prep: weights (1 dispatch), x conversion, CSR build ---
    prep_w_k<<<1056, blk, 0, stream>>>(Wq, Wk, Wv, Wg, Wm, Wc1, Wrel, Wroot, WT);
    cvt_x_k<<<BNC_ / 1024, blk, 0, stream>>>(x, xb, cat1, cat2);
    hipMemsetAsync(deg, 0, 589824, stream);
    count2_k<<<E_ / 256, blk, 0, stream>>>(edst, et, deg, cnt8i);
    scan_k<<<1, blk, 0, stream>>>(deg, rowptr, cursor);
    fill_k<<<E_ / 256, blk, 0, stream>>>(esrc, edst, et, cursor, elist);

    // --- fused QKV projection: qkv[16384,768] ---
    gemm_bf16<0><<<dim3(6, 128, 1), blk, 0, stream>>>(
        xb, 256, 0, WqkvT, 256, 0, qkv, 768, 0, bq, bk, bv, 256);
    vtrans_k<<<dim3(8, 32, 16), blk, 0, stream>>>(qkv, vtb);

    // --- attention: QK^T, softmax, PV (128-tile; best measured config) ---
    gemm_bf16<0><<<dim3(8, 8, 16), blk, 0, stream>>>(
        qkv, 768, 786432, qkv + 256, 768, 786432, sP, 1024, 1048576, nullptr, nullptr, nullptr, 256);
    softmax_k<<<BN_, blk, 0, stream>>>(sP);
    gemm_bf16<0><<<dim3(2, 8, 16), blk, 0, stream>>>(
        sP, 1024, 1048576, vtb, 1024, 262144, cat1, 512, 524288, nullptr, nullptr, nullptr, 1024);

    // --- gate (64-tile depth-4, 1024 blocks), blend+LN ---
    gemm64_bf16<2><<<dim3(4, 256, 1), blk, 0, stream>>>(
        cat1, 512, 0, WgT, 512, 0, gate, 256, 0, bg, 512);
    blend_ln_k<<<BN_ / 4, blk, 0, stream>>>(gate, cat1, x, valid, lag, lab);

    // --- confidence (64-tile depth-4, 512 blocks) + weighted ---
    gemm64_bf16<1><<<dim3(2, 256, 1), blk, 0, stream>>>(
        valid, 256, 0, Wc1T, 256, 0, t1, 128, 0, bc1, 256);
    conf_w_k<<<BN_ / 4, blk, 0, stream>>>(t1, Wc2, bc2, valid, conf, cat2);

    // --- mixer (64-tile depth-4, 1024 blocks) + LN1 ---
    gemm64_bf16<1><<<dim3(4, 256, 1), blk, 0, stream>>>(
        cat2, 512, 0, WmT, 512, 0, xm, 256, 0, bm, 512);
    ln_k<0><<<BN_ / 4, blk, 0, stream>>>(xm, xn, l1g, l1b);

    // --- RGCN: one GEMM (128-tile, 2304 blocks, XCD-swizzled), gather + LN2 ---
    gemm_bf16<0><<<dim3(18, 128, 1), blk, 0, stream>>>(
        xn, 256, 0, WBIG, 256, 0, hbuf, 2304, 0, nullptr, nullptr, nullptr, 256);
    gather_ln_k<<<BN_ / 4, blk, 0, stream>>>(rowptr, elist, hbuf, cnt8i, brg, l2g, l2b, xr);

    // --- pool + head ---
    pool1_k<<<dim3(B_, 16), blk, 0, stream>>>(xr, conf, part);
    pool2_k<<<B_, blk, 0, stream>>>(part, conf, Wh, bh, outp);
}

// Round 12
// 261.208 us; speedup vs baseline: 1.5127x; 1.0100x over previous
//
#include <hip/hip_runtime.h>
#include <hip/hip_bf16.h>

#define B_ 16
#define N_ 1024
#define C_ 256
#define R_ 8
#define E_ 262144
#define NS_ 32
#define BN_ (B_*N_)
#define BNC_ (BN_*C_)

typedef __hip_bfloat16 bf16;
typedef __attribute__((ext_vector_type(4))) float f32x4;
typedef __attribute__((ext_vector_type(8))) short bf16x8;

__device__ __forceinline__ float b2f(bf16 x) { return __bfloat162float(x); }
__device__ __forceinline__ bf16  f2b(float x) { return __float2bfloat16(x); }
__device__ __forceinline__ float us2f(unsigned short u) { return __uint_as_float((unsigned)u << 16); }

// async global->LDS, 16B per lane (wave-uniform LDS base + lane*16 implicit)
__device__ __forceinline__ void gload16(const void* g, void* l) {
    auto gp = (const __attribute__((address_space(1))) void*)(unsigned long long)g;
    auto lp = (__attribute__((address_space(3))) void*)(unsigned)(unsigned long long)l;
    __builtin_amdgcn_global_load_lds(gp, lp, 16, 0, 0);
}

// ---------------- bf16 MFMA GEMM (128x128 tile): C = act(A @ B^T + bias) ----------------
// Depth-3 pipeline: 3 LDS buffers (48 KB -> 3 blocks/CU), stage issued 3 iters
// ahead, vmcnt ladder 8/4/0 (never drains mid-loop). XOR slot swizzle both
// sides (rule #21). T1 XCD-aware block swizzle (bijective when nwg % 8 == 0).
template<int ACT>
__global__ __launch_bounds__(256) void gemm_bf16(
    const bf16* __restrict__ A, int lda, long long sA,
    const bf16* __restrict__ Bm, int ldb, long long sB,
    bf16* __restrict__ Cc, int ldc, long long sC,
    const float* __restrict__ bias, const float* __restrict__ bias2,
    const float* __restrict__ bias3, int K)
{
    __shared__ short sbuf[24576];        // 48 KB: A0..A2 @ cur*4096, B0..B2 @ 12288+cur*4096
    const int tid = threadIdx.x;
    const int lane = tid & 63, w = tid >> 6;
    const int wr = w >> 1, wc = w & 1;

    const int gx = gridDim.x;
    const int nwg = gx * gridDim.y;
    int id = blockIdx.y * gx + blockIdx.x;
    if ((nwg & 7) == 0) { const int cpx = nwg >> 3; id = (id & 7) * cpx + (id >> 3); }
    const int bm = (id / gx) * 128, bn = (id % gx) * 128;

    const bf16* Ab = A + (size_t)blockIdx.z * sA;
    const bf16* Bb = Bm + (size_t)blockIdx.z * sB;
    bf16* Cb = Cc + (size_t)blockIdx.z * sC;

    const int rg = lane >> 2;
    const int kswz = ((lane & 3) ^ ((rg >> 1) & 3)) * 8;

    f32x4 acc[4][4];
    const f32x4 zz = {0.f, 0.f, 0.f, 0.f};
    #pragma unroll
    for (int i = 0; i < 4; ++i)
        #pragma unroll
        for (int j = 0; j < 4; ++j) acc[i][j] = zz;

    const int fr = lane & 15;
    const int fm = lane >> 4;
    const int fslot = (fm ^ ((fr >> 1) & 3)) * 8;

    const int NI = K >> 5;

#define STAGE_AB(bi, kk) do {                                                          \
    _Pragma("unroll")                                                                  \
    for (int t_ = 0; t_ < 2; ++t_) {                                                   \
        gload16(Ab + (size_t)(bm + t_*64 + w*16 + rg) * lda + (kk) + kswz,             \
                sbuf + (bi)*4096 + t_*2048 + w*512);                                   \
        gload16(Bb + (size_t)(bn + t_*64 + w*16 + rg) * ldb + (kk) + kswz,             \
                sbuf + 12288 + (bi)*4096 + t_*2048 + w*512);                           \
    } } while (0)

    STAGE_AB(0, 0);
    if (NI > 1) STAGE_AB(1, 32);
    if (NI > 2) STAGE_AB(2, 64);

    int cur = 0;
    for (int i = 0; i < NI; ++i) {
        if (i + 2 < NI)      asm volatile("s_waitcnt vmcnt(8)" ::: "memory");
        else if (i + 1 < NI) asm volatile("s_waitcnt vmcnt(4)" ::: "memory");
        else                 asm volatile("s_waitcnt vmcnt(0)" ::: "memory");
        __builtin_amdgcn_s_barrier();
        __builtin_amdgcn_sched_barrier(0);

        bf16x8 af[4], bfr[4];
        const short* Ac = sbuf + cur * 4096;
        const short* Bc = sbuf + 12288 + cur * 4096;
        #pragma unroll
        for (int ii = 0; ii < 4; ++ii)
            af[ii] = *(const bf16x8*)&Ac[(wr*64 + ii*16 + fr)*32 + fslot];
        #pragma unroll
        for (int jj = 0; jj < 4; ++jj)
            bfr[jj] = *(const bf16x8*)&Bc[(wc*64 + jj*16 + fr)*32 + fslot];

        asm volatile("s_waitcnt lgkmcnt(0)" ::: "memory");
        __builtin_amdgcn_s_barrier();
        __builtin_amdgcn_sched_barrier(0);
        if (i + 3 < NI) STAGE_AB(cur, (i + 3) * 32);

        #pragma unroll
        for (int ii = 0; ii < 4; ++ii)
            #pragma unroll
            for (int jj = 0; jj < 4; ++jj)
                acc[ii][jj] = __builtin_amdgcn_mfma_f32_16x16x32_bf16(af[ii], bfr[jj], acc[ii][jj], 0, 0, 0);
        cur = (cur == 2) ? 0 : cur + 1;
    }
#undef STAGE_AB

    __syncthreads();
    const int er = (lane >> 4) * 4, ec = lane & 15;
    #pragma unroll
    for (int half = 0; half < 2; ++half) {
        if (wr == half) {
            #pragma unroll
            for (int j = 0; j < 4; ++j) {
                const int col = bn + wc*64 + j*16 + ec;
                float bvv = 0.0f;
                if (bias) {
                    const int seg = col >> 8;
                    const float* bp = (seg == 0) ? bias : (seg == 1 ? bias2 : bias3);
                    bvv = bp[col & 255];
                }
                #pragma unroll
                for (int i = 0; i < 4; ++i) {
                    #pragma unroll
                    for (int p = 0; p < 4; ++p) {
                        float val = acc[i][j][p] + bvv;
                        if (ACT == 1) val = fmaxf(val, 0.0f);
                        if (ACT == 2) val = 1.0f / (1.0f + __expf(-val));
                        *(bf16*)&sbuf[(i*16 + er + p)*136 + wc*64 + j*16 + ec] = f2b(val);
                    }
                }
            }
        }
        __syncthreads();
        #pragma unroll
        for (int it = 0; it < 4; ++it) {
            const int ch = tid + it*256;
            const int row = ch >> 4, cp = (ch & 15) * 8;
            *(bf16x8*)&Cb[(size_t)(bm + half*64 + row) * ldc + bn + cp] =
                *(const bf16x8*)&sbuf[row*136 + cp];
        }
        __syncthreads();
    }
}

// ---------------- bf16 MFMA GEMM (64x64 tile, depth-4 pipeline) ----------------
// For the serial latency-bound chain (gate/conf/mixer). 4 LDS buffers (32 KB),
// vmcnt ladder 6/4/2/0 keeps 3 tiles in flight. XOR swizzle both sides.
template<int ACT>
__global__ __launch_bounds__(256) void gemm64_bf16(
    const bf16* __restrict__ A, int lda, long long sA,
    const bf16* __restrict__ Bm, int ldb, long long sB,
    bf16* __restrict__ Cc, int ldc, long long sC,
    const float* __restrict__ bias, int K)
{
    __shared__ short sbuf[16384];        // 32 KB: A0..A3 @ bi*2048, B0..B3 @ 8192+bi*2048
    const int tid = threadIdx.x;
    const int lane = tid & 63, w = tid >> 6;
    const int wr = w >> 1, wc = w & 1;   // 2x2 quadrants of 32x32

    const int gx = gridDim.x;
    const int nwg = gx * gridDim.y;
    int id = blockIdx.y * gx + blockIdx.x;
    if ((nwg & 7) == 0) { const int cpx = nwg >> 3; id = (id & 7) * cpx + (id >> 3); }
    const int bm = (id / gx) * 64, bn = (id % gx) * 64;

    const bf16* Ab = A + (size_t)blockIdx.z * sA;
    const bf16* Bb = Bm + (size_t)blockIdx.z * sB;
    bf16* Cb = Cc + (size_t)blockIdx.z * sC;

    const int rg = lane >> 2;
    const int kswz = ((lane & 3) ^ ((rg >> 1) & 3)) * 8;

    f32x4 acc[2][2];
    const f32x4 zz = {0.f, 0.f, 0.f, 0.f};
    #pragma unroll
    for (int i = 0; i < 2; ++i)
        #pragma unroll
        for (int j = 0; j < 2; ++j) acc[i][j] = zz;

    const int fr = lane & 15;
    const int fm = lane >> 4;
    const int fslot = (fm ^ ((fr >> 1) & 3)) * 8;

    const int NI = K >> 5;

#define STAGE64(bi, kk) do {                                                           \
    gload16(Ab + (size_t)(bm + w*16 + rg) * lda + (kk) + kswz,                         \
            sbuf + (bi)*2048 + w*512);                                                 \
    gload16(Bb + (size_t)(bn + w*16 + rg) * ldb + (kk) + kswz,                         \
            sbuf + 8192 + (bi)*2048 + w*512);                                          \
    } while (0)

    STAGE64(0, 0);
    if (NI > 1) STAGE64(1, 32);
    if (NI > 2) STAGE64(2, 64);
    if (NI > 3) STAGE64(3, 96);

    for (int i = 0; i < NI; ++i) {
        const int cur = i & 3;
        if (i + 3 < NI)      asm volatile("s_waitcnt vmcnt(6)" ::: "memory");
        else if (i + 2 < NI) asm volatile("s_waitcnt vmcnt(4)" ::: "memory");
        else if (i + 1 < NI) asm volatile("s_waitcnt vmcnt(2)" ::: "memory");
        else                 asm volatile("s_waitcnt vmcnt(0)" ::: "memory");
        __builtin_amdgcn_s_barrier();
        __builtin_amdgcn_sched_barrier(0);

        bf16x8 af[2], bfr[2];
        const short* Ac = sbuf + cur * 2048;
        const short* Bc = sbuf + 4096*2 + cur * 2048;
        #pragma unroll
        for (int ii = 0; ii < 2; ++ii)
            af[ii] = *(const bf16x8*)&Ac[(wr*32 + ii*16 + fr)*32 + fslot];
        #pragma unroll
        for (int jj = 0; jj < 2; ++jj)
            bfr[jj] = *(const bf16x8*)&Bc[(wc*32 + jj*16 + fr)*32 + fslot];

        asm volatile("s_waitcnt lgkmcnt(0)" ::: "memory");
        __builtin_amdgcn_s_barrier();
        __builtin_amdgcn_sched_barrier(0);
        if (i + 4 < NI) STAGE64(cur, (i + 4) * 32);

        #pragma unroll
        for (int ii = 0; ii < 2; ++ii)
            #pragma unroll
            for (int jj = 0; jj < 2; ++jj)
                acc[ii][jj] = __builtin_amdgcn_mfma_f32_16x16x32_bf16(af[ii], bfr[jj], acc[ii][jj], 0, 0, 0);
    }
#undef STAGE64

    __syncthreads();
    const int er = (lane >> 4) * 4, ec = lane & 15;
    #pragma unroll
    for (int j = 0; j < 2; ++j) {
        const int col = bn + wc*32 + j*16 + ec;
        const float bvv = bias ? bias[col & 255] : 0.0f;
        #pragma unroll
        for (int i = 0; i < 2; ++i) {
            #pragma unroll
            for (int p = 0; p < 4; ++p) {
                float val = acc[i][j][p] + bvv;
                if (ACT == 1) val = fmaxf(val, 0.0f);
                if (ACT == 2) val = 1.0f / (1.0f + __expf(-val));
                *(bf16*)&sbuf[(wr*32 + i*16 + er + p)*72 + wc*32 + j*16 + ec] = f2b(val);
            }
        }
    }
    __syncthreads();
    #pragma unroll
    for (int it = 0; it < 2; ++it) {
        const int ch = tid + it*256;
        const int row = ch >> 3, cp = (ch & 7) * 8;
        *(bf16x8*)&Cb[(size_t)(bm + row) * ldc + bn + cp] =
            *(const bf16x8*)&sbuf[row*72 + cp];
    }
}

// ---------------- all weight transposes fp32[K,Nn] -> bf16[Nn,K], one dispatch ----------------
__global__ __launch_bounds__(256) void prep_w_k(
    const float* __restrict__ Wq, const float* __restrict__ Wk, const float* __restrict__ Wv,
    const float* __restrict__ Wg, const float* __restrict__ Wm, const float* __restrict__ Wc1,
    const float* __restrict__ Wrel, const float* __restrict__ Wroot, bf16* __restrict__ WT)
{
    int t = blockIdx.x;
    const float* in; bf16* out; int K, Nn;
    if (t < 192)      { int wsel = t >> 6; t &= 63;
                        in = wsel == 0 ? Wq : (wsel == 1 ? Wk : Wv);
                        out = WT + wsel*65536; K = 256; Nn = 256; }
    else if (t < 320) { t -= 192; in = Wg;  out = WT + 196608; K = 512; Nn = 256; }
    else if (t < 448) { t -= 320; in = Wm;  out = WT + 327680; K = 512; Nn = 256; }
    else if (t < 480) { t -= 448; in = Wc1; out = WT + 458752; K = 256; Nn = 128; }
    else if (t < 992) { t -= 480; int r = t >> 6; t &= 63;
                        in = Wrel + (size_t)r*65536; out = WT + 491520 + r*65536; K = 256; Nn = 256; }
    else              { t -= 992; in = Wroot; out = WT + 491520 + 524288; K = 256; Nn = 256; }
    const int tpr = Nn >> 5;
    const int n0 = (t % tpr) * 32, k0 = (t / tpr) * 32;
    __shared__ float tile[32][33];
    const int tx = threadIdx.x & 31, ty = threadIdx.x >> 5;
    #pragma unroll
    for (int i = 0; i < 4; ++i) {
        int r = ty + i*8;
        tile[r][tx] = in[(size_t)(k0 + r) * Nn + n0 + tx];
    }
    __syncthreads();
    #pragma unroll
    for (int i = 0; i < 4; ++i) {
        int r = ty + i*8;
        out[(size_t)(n0 + r) * K + k0 + tx] = f2b(tile[tx][r]);
    }
}

// ---------------- V^T: qkv V-part [1024,256] (ld 768) -> vtb [256,1024] per batch ----------------
__global__ __launch_bounds__(256) void vtrans_k(
    const bf16* __restrict__ in, bf16* __restrict__ out)
{
    __shared__ float tile[32][33];
    in  += (size_t)blockIdx.z * 786432 + 512;
    out += (size_t)blockIdx.z * 262144;
    const int n0 = blockIdx.x * 32, k0 = blockIdx.y * 32;
    const int tx = threadIdx.x & 31, ty = threadIdx.x >> 5;
    #pragma unroll
    for (int i = 0; i < 4; ++i) {
        int r = ty + i*8;
        tile[r][tx] = b2f(in[(size_t)(k0 + r) * 768 + n0 + tx]);
    }
    __syncthreads();
    #pragma unroll
    for (int i = 0; i < 4; ++i) {
        int r = ty + i*8;
        out[(size_t)(n0 + r) * 1024 + k0 + tx] = f2b(tile[tx][r]);
    }
}

// ---------------- x fp32 -> bf16 (xb, cat1 right half, cat2 left half), 4 el/thread ----------------
__global__ __launch_bounds__(256) void cvt_x_k(const float* __restrict__ x,
    bf16* __restrict__ xb, bf16* __restrict__ cat1, bf16* __restrict__ cat2)
{
    const int i4 = (blockIdx.x * 256 + threadIdx.x) * 4;
    const float4 xv = *(const float4*)(x + i4);
    bf16 bv[4] = { f2b(xv.x), f2b(xv.y), f2b(xv.z), f2b(xv.w) };
    const ushort4 pack = *(const ushort4*)bv;
    const int row = i4 >> 8, col = i4 & 255;
    *(ushort4*)(xb + i4) = pack;
    *(ushort4*)(cat1 + (size_t)row * 512 + 256 + col) = pack;
    *(ushort4*)(cat2 + (size_t)row * 512 + col) = pack;
}

// ---------------- row softmax over 1024 bf16 scores in place (pre-scale 1/16) ----------------
__global__ __launch_bounds__(256) void softmax_k(bf16* __restrict__ s)
{
    const int row = blockIdx.x, tid = threadIdx.x;
    const int lane = tid & 63, wid = tid >> 6;
    bf16* rp = s + (size_t)row * 1024 + tid * 4;
    __shared__ float red[8];
    const ushort4 sv = *(const ushort4*)rp;
    float v0 = us2f(sv.x) * 0.0625f, v1 = us2f(sv.y) * 0.0625f;
    float v2 = us2f(sv.z) * 0.0625f, v3 = us2f(sv.w) * 0.0625f;
    float m = fmaxf(fmaxf(v0, v1), fmaxf(v2, v3));
    #pragma unroll
    for (int o = 32; o >= 1; o >>= 1) m = fmaxf(m, __shfl_xor(m, o));
    if (lane == 0) red[wid] = m;
    __syncthreads();
    const float mx = fmaxf(fmaxf(red[0], red[1]), fmaxf(red[2], red[3]));
    float e0 = __expf(v0 - mx), e1 = __expf(v1 - mx), e2 = __expf(v2 - mx), e3 = __expf(v3 - mx);
    float sm = e0 + e1 + e2 + e3;
    #pragma unroll
    for (int o = 32; o >= 1; o >>= 1) sm += __shfl_xor(sm, o);
    if (lane == 0) red[4 + wid] = sm;
    __syncthreads();
    const float inv = 1.0f / (red[4] + red[5] + red[6] + red[7]);
    bf16 ov[4] = { f2b(e0 * inv), f2b(e1 * inv), f2b(e2 * inv), f2b(e3 * inv) };
    *(ushort4*)rp = *(const ushort4*)ov;
}

// ---------------- LN over C=256 (wave per row, 4 ch/lane), bf16 in/out ----------------
template<int RELU>
__global__ __launch_bounds__(256) void ln_k(
    const bf16* __restrict__ in, bf16* __restrict__ out,
    const float* __restrict__ g, const float* __restrict__ bta)
{
    const int node = blockIdx.x * 4 + (threadIdx.x >> 6);
    const int lane = threadIdx.x & 63;
    const ushort4 iv = *(const ushort4*)(in + (size_t)node * 256 + lane * 4);
    float v0 = us2f(iv.x), v1 = us2f(iv.y), v2 = us2f(iv.z), v3 = us2f(iv.w);
    float s  = v0 + v1 + v2 + v3;
    float sq = v0*v0 + v1*v1 + v2*v2 + v3*v3;
    #pragma unroll
    for (int o = 32; o >= 1; o >>= 1) { s += __shfl_xor(s, o); sq += __shfl_xor(sq, o); }
    const float mean = s * (1.0f / 256.0f);
    const float var  = sq * (1.0f / 256.0f) - mean * mean;
    const float rs = rsqrtf(var + 1e-5f);
    const float4 gv = *(const float4*)(g + lane * 4);
    const float4 bv = *(const float4*)(bta + lane * 4);
    float y0 = (v0 - mean) * rs * gv.x + bv.x;
    float y1 = (v1 - mean) * rs * gv.y + bv.y;
    float y2 = (v2 - mean) * rs * gv.z + bv.z;
    float y3 = (v3 - mean) * rs * gv.w + bv.w;
    if (RELU) { y0 = fmaxf(y0, 0.f); y1 = fmaxf(y1, 0.f); y2 = fmaxf(y2, 0.f); y3 = fmaxf(y3, 0.f); }
    bf16 ov[4] = { f2b(y0), f2b(y1), f2b(y2), f2b(y3) };
    *(ushort4*)(out + (size_t)node * 256 + lane * 4) = *(const ushort4*)ov;
}

// ---------------- gated blend + LN (wave per row; residual from bf16 xb) ----------------
__global__ __launch_bounds__(256) void blend_ln_k(
    const bf16* __restrict__ gate, const bf16* __restrict__ cat1,
    const bf16* __restrict__ xb, bf16* __restrict__ valid,
    const float* __restrict__ g, const float* __restrict__ bta)
{
    const int node = blockIdx.x * 4 + (threadIdx.x >> 6);
    const int lane = threadIdx.x & 63;
    const ushort4 gt4 = *(const ushort4*)(gate + (size_t)node * 256 + lane * 4);
    const ushort4 ao4 = *(const ushort4*)(cat1 + (size_t)node * 512 + lane * 4);
    const ushort4 xv4 = *(const ushort4*)(xb + (size_t)node * 256 + lane * 4);
    float g0 = us2f(gt4.x), g1 = us2f(gt4.y), g2 = us2f(gt4.z), g3 = us2f(gt4.w);
    float v0 = g0 * us2f(ao4.x) + (1.f - g0) * us2f(xv4.x);
    float v1 = g1 * us2f(ao4.y) + (1.f - g1) * us2f(xv4.y);
    float v2 = g2 * us2f(ao4.z) + (1.f - g2) * us2f(xv4.z);
    float v3 = g3 * us2f(ao4.w) + (1.f - g3) * us2f(xv4.w);
    float s  = v0 + v1 + v2 + v3;
    float sq = v0*v0 + v1*v1 + v2*v2 + v3*v3;
    #pragma unroll
    for (int o = 32; o >= 1; o >>= 1) { s += __shfl_xor(s, o); sq += __shfl_xor(sq, o); }
    const float mean = s * (1.0f / 256.0f);
    const float var  = sq * (1.0f / 256.0f) - mean * mean;
    const float rs = rsqrtf(var + 1e-5f);
    const float4 gv = *(const float4*)(g + lane * 4);
    const float4 bv = *(const float4*)(bta + lane * 4);
    bf16 ov[4] = { f2b((v0 - mean) * rs * gv.x + bv.x), f2b((v1 - mean) * rs * gv.y + bv.y),
                   f2b((v2 - mean) * rs * gv.z + bv.z), f2b((v3 - mean) * rs * gv.w + bv.w) };
    *(ushort4*)(valid + (size_t)node * 256 + lane * 4) = *(const ushort4*)ov;
}

// ---------------- confidence layer2 + weighted (wave per node) ----------------
__global__ __launch_bounds__(256) void conf_w_k(
    const bf16* __restrict__ t1, const float* __restrict__ Wc2, const float* __restrict__ bc2,
    const bf16* __restrict__ valid, float* __restrict__ conf, bf16* __restrict__ cat2)
{
    const int node = blockIdx.x * 4 + (threadIdx.x >> 6);
    const int lane = threadIdx.x & 63;
    float a = b2f(t1[(size_t)node * 128 + lane]) * Wc2[lane]
            + b2f(t1[(size_t)node * 128 + 64 + lane]) * Wc2[64 + lane];
    #pragma unroll
    for (int o = 32; o >= 1; o >>= 1) a += __shfl_xor(a, o);
    const float c = 1.0f / (1.0f + __expf(-(a + bc2[0])));
    if (lane == 0) conf[node] = c;
    const ushort4 vv = *(const ushort4*)(valid + (size_t)node * 256 + lane * 4);
    bf16 ov[4] = { f2b(us2f(vv.x) * c), f2b(us2f(vv.y) * c), f2b(us2f(vv.z) * c), f2b(us2f(vv.w) * c) };
    *(ushort4*)(cat2 + (size_t)node * 512 + 256 + lane * 4) = *(const ushort4*)ov;
}

// ---------------- CSR build ----------------
__global__ __launch_bounds__(256) void count2_k(
    const int* __restrict__ dst, const int* __restrict__ et,
    int* __restrict__ deg, int* __restrict__ cnt8)
{
    const int e = blockIdx.x * 256 + threadIdx.x;
    if (e < E_) {
        const int d = dst[e];
        atomicAdd(&deg[d], 1);
        atomicAdd(&cnt8[d * 8 + et[e]], 1);
    }
}

__global__ __launch_bounds__(256) void scan_k(
    const int* __restrict__ deg, int* __restrict__ rowptr, int* __restrict__ cursor)
{
    __shared__ int part[256];
    const int tid = threadIdx.x;
    const int base = tid * 64;
    int s = 0;
    for (int i = 0; i < 64; ++i) s += deg[base + i];
    part[tid] = s; __syncthreads();
    for (int off = 1; off < 256; off <<= 1) {
        int t = (tid >= off) ? part[tid - off] : 0;
        __syncthreads();
        part[tid] += t;
        __syncthreads();
    }
    int run = (tid == 0) ? 0 : part[tid - 1];
    for (int i = 0; i < 64; ++i) {
        rowptr[base + i] = run;
        cursor[base + i] = run;
        run += deg[base + i];
    }
    if (tid == 255) rowptr[BN_] = run;
}

__global__ __launch_bounds__(256) void fill_k(
    const int* __restrict__ src, const int* __restrict__ dst, const int* __restrict__ et,
    int* __restrict__ cursor, int* __restrict__ elist)
{
    const int e = blockIdx.x * 256 + threadIdx.x;
    if (e < E_) {
        const int pos = atomicAdd(&cursor[dst[e]], 1);
        elist[pos] = src[e] | (et[e] << 16);
    }
}

// ---------------- RGCN gather + root + bias + LN2 + relu (wave per node) ----------------
// 4-edge unrolled: four independent h-row loads in flight per wave.
__global__ __launch_bounds__(256) void gather_ln_k(
    const int* __restrict__ rowptr, const int* __restrict__ elist,
    const bf16* __restrict__ h, const int* __restrict__ cnt8,
    const float* __restrict__ brg,
    const float* __restrict__ g, const float* __restrict__ bta,
    bf16* __restrict__ xr)
{
    const int node = blockIdx.x * 4 + (threadIdx.x >> 6);
    const int lane = threadIdx.x & 63;
    const int e0 = rowptr[node], e1 = rowptr[node + 1];
    float invc[8];
    #pragma unroll
    for (int r = 0; r < 8; ++r)
        invc[r] = 1.0f / fmaxf((float)cnt8[node * 8 + r], 1.0f);
    float a0 = 0.f, a1 = 0.f, a2 = 0.f, a3 = 0.f;
    int e = e0;
    for (; e + 3 < e1; e += 4) {
        const int p0 = elist[e], p1 = elist[e+1], p2 = elist[e+2], p3 = elist[e+3];
        const float w0 = invc[p0 >> 16], w1 = invc[p1 >> 16];
        const float w2 = invc[p2 >> 16], w3 = invc[p3 >> 16];
        const ushort4 h0 = *(const ushort4*)(h + (size_t)(p0 & 0xffff) * 2304 + (p0 >> 16) * 256 + lane * 4);
        const ushort4 h1 = *(const ushort4*)(h + (size_t)(p1 & 0xffff) * 2304 + (p1 >> 16) * 256 + lane * 4);
        const ushort4 h2 = *(const ushort4*)(h + (size_t)(p2 & 0xffff) * 2304 + (p2 >> 16) * 256 + lane * 4);
        const ushort4 h3 = *(const ushort4*)(h + (size_t)(p3 & 0xffff) * 2304 + (p3 >> 16) * 256 + lane * 4);
        a0 += w0 * us2f(h0.x) + w1 * us2f(h1.x) + w2 * us2f(h2.x) + w3 * us2f(h3.x);
        a1 += w0 * us2f(h0.y) + w1 * us2f(h1.y) + w2 * us2f(h2.y) + w3 * us2f(h3.y);
        a2 += w0 * us2f(h0.z) + w1 * us2f(h1.z) + w2 * us2f(h2.z) + w3 * us2f(h3.z);
        a3 += w0 * us2f(h0.w) + w1 * us2f(h1.w) + w2 * us2f(h2.w) + w3 * us2f(h3.w);
    }
    for (; e < e1; ++e) {
        const int pe = elist[e];
        const float wgt = invc[pe >> 16];
        const ushort4 hv = *(const ushort4*)(h + (size_t)(pe & 0xffff) * 2304 + (pe >> 16) * 256 + lane * 4);
        a0 += wgt * us2f(hv.x); a1 += wgt * us2f(hv.y);
        a2 += wgt * us2f(hv.z); a3 += wgt * us2f(hv.w);
    }
    const ushort4 rv = *(const ushort4*)(h + (size_t)node * 2304 + 2048 + lane * 4);
    const float4 bg4 = *(const float4*)(brg + lane * 4);
    const float v0 = a0 + us2f(rv.x) + bg4.x, v1 = a1 + us2f(rv.y) + bg4.y;
    const float v2 = a2 + us2f(rv.z) + bg4.z, v3 = a3 + us2f(rv.w) + bg4.w;
    float s  = v0 + v1 + v2 + v3;
    float sq = v0*v0 + v1*v1 + v2*v2 + v3*v3;
    #pragma unroll
    for (int m = 32; m >= 1; m >>= 1) { s += __shfl_xor(s, m); sq += __shfl_xor(sq, m); }
    const float mean = s * (1.0f / 256.0f);
    const float var  = sq * (1.0f / 256.0f) - mean * mean;
    const float rs = rsqrtf(var + 1e-5f);
    const float4 gv = *(const float4*)(g + lane * 4);
    const float4 bv = *(const float4*)(bta + lane * 4);
    bf16 tb[4] = { f2b(fmaxf((v0 - mean) * rs * gv.x + bv.x, 0.f)),
                   f2b(fmaxf((v1 - mean) * rs * gv.y + bv.y, 0.f)),
                   f2b(fmaxf((v2 - mean) * rs * gv.z + bv.z, 0.f)),
                   f2b(fmaxf((v3 - mean) * rs * gv.w + bv.w, 0.f)) };
    *(ushort4*)(xr + (size_t)node * 256 + lane * 4) = *(const ushort4*)tb;
}

// ---------------- pooling stage 1 ----------------
__global__ __launch_bounds__(256) void pool1_k(
    const bf16* __restrict__ xr, const float* __restrict__ conf, float* __restrict__ partial)
{
    const int b = blockIdx.x, chunk = blockIdx.y, c = threadIdx.x;
    float acc = 0.0f;
    for (int n = 0; n < 64; ++n) {
        const int node = b * 1024 + chunk * 64 + n;
        acc += conf[node] * b2f(xr[(size_t)node * 256 + c]);
    }
    partial[(size_t)(b * 16 + chunk) * 256 + c] = acc;
}

// ---------------- pooling stage 2 + head ----------------
__global__ __launch_bounds__(256) void pool2_k(
    const float* __restrict__ partial, const float* __restrict__ conf,
    const float* __restrict__ Wh, const float* __restrict__ bh, float* __restrict__ out)
{
    const int b = blockIdx.x, tid = threadIdx.x;
    __shared__ float red[256];
    __shared__ float pooled[256];
    float pc = 0.0f;
    for (int ch = 0; ch < 16; ++ch) pc += partial[(size_t)(b * 16 + ch) * 256 + tid];
    float s = conf[b * 1024 + tid] + conf[b * 1024 + 256 + tid]
            + conf[b * 1024 + 512 + tid] + conf[b * 1024 + 768 + tid];
    red[tid] = s; __syncthreads();
    for (int st = 128; st > 0; st >>= 1) { if (tid < st) red[tid] += red[tid + st]; __syncthreads(); }
    const float denom = fmaxf(red[0], 1e-8f);
    pooled[tid] = pc / denom;
    __syncthreads();
    if (tid < NS_) {
        float o = bh[tid];
        for (int c = 0; c < 256; ++c) o += pooled[c] * Wh[c * NS_ + tid];
        out[b * NS_ + tid] = o;
    }
}

extern "C" void kernel_launch(void* const* d_in, const int* in_sizes, int n_in,
                              void* d_out, int out_size, void* d_ws, size_t ws_size,
                              hipStream_t stream) {
    const float* x    = (const float*)d_in[0];
    const int*   ei   = (const int*)d_in[1];
    const int*   et   = (const int*)d_in[2];
    const float* Wq   = (const float*)d_in[3];  const float* bq  = (const float*)d_in[4];
    const float* Wk   = (const float*)d_in[5];  const float* bk  = (const float*)d_in[6];
    const float* Wv   = (const float*)d_in[7];  const float* bv  = (const float*)d_in[8];
    const float* Wg   = (const float*)d_in[9];  const float* bg  = (const float*)d_in[10];
    const float* lag  = (const float*)d_in[11]; const float* lab = (const float*)d_in[12];
    const float* Wc1  = (const float*)d_in[13]; const float* bc1 = (const float*)d_in[14];
    const float* Wc2  = (const float*)d_in[15]; const float* bc2 = (const float*)d_in[16];
    const float* Wm   = (const float*)d_in[17]; const float* bm  = (const float*)d_in[18];
    const float* l1g  = (const float*)d_in[19]; const float* l1b = (const float*)d_in[20];
    const float* Wrel = (const float*)d_in[21]; const float* Wroot = (const float*)d_in[22];
    const float* brg  = (const float*)d_in[23];
    const float* l2g  = (const float*)d_in[24]; const float* l2b = (const float*)d_in[25];
    const float* Wh   = (const float*)d_in[26]; const float* bh  = (const float*)d_in[27];
    const int* esrc = ei;
    const int* edst = ei + E_;

    char* w8 = (char*)d_ws;
    bf16*  qkv   = (bf16*)(w8 + 0);            // [16384,768]
    bf16*  hbuf  = (bf16*)(w8 + 0);            // [16384,2304] (reuses qkv/sP region)
    bf16*  sP    = (bf16*)(w8 + 25165824);     // [16x1024x1024]
    bf16*  cat1  = (bf16*)(w8 + 58720256);     // [aout|xb] ld 512
    bf16*  cat2  = (bf16*)(w8 + 75497472);     // [xb|weighted] ld 512
    bf16*  gate  = (bf16*)(w8 + 92274688);
    bf16*  valid = (bf16*)(w8 + 100663296);
    bf16*  t1    = (bf16*)(w8 + 109051904);
    bf16*  xm    = (bf16*)(w8 + 113246208);
    bf16*  xb    = (bf16*)(w8 + 121634816);
    bf16*  xn    = (bf16*)(w8 + 130023424);
    bf16*  vtb   = (bf16*)(w8 + 138412032);
    bf16*  xr    = (bf16*)(w8 + 146800640);
    float* conf  = (float*)(w8 + 155189248);
    float* part  = (float*)(w8 + 155254784);
    bf16*  WT    = (bf16*)(w8 + 155516928);
    int*  deg    = (int*)(w8 + 157679616);
    int*  cnt8i  = (int*)(w8 + 157745152);
    int*  rowptr = (int*)(w8 + 158269440);
    int*  cursor = (int*)(w8 + 158335232);
    int*  elist  = (int*)(w8 + 158400768);
    bf16* WqkvT = WT;                  // [768,256]
    bf16* WgT   = WT + 196608;         // [256,512]
    bf16* WmT   = WT + 327680;         // [256,512]
    bf16* Wc1T  = WT + 458752;         // [128,256]
    bf16* WBIG  = WT + 491520;         // [2304,256]
    float* outp = (float*)d_out;

    dim3 blk(256);

    // --- prep: weights (1 dispatch), x conversion, CSR build ---
    prep_w_k<<<1056, blk, 0, stream>>>(Wq, Wk, Wv, Wg, Wm, Wc1, Wrel, Wroot, WT);
    cvt_x_k<<<BNC_ / 1024, blk, 0, stream>>>(x, xb, cat1, cat2);
    hipMemsetAsync(deg, 0, 589824, stream);
    count2_k<<<E_ / 256, blk, 0, stream>>>(edst, et, deg, cnt8i);
    scan_k<<<1, blk, 0, stream>>>(deg, rowptr, cursor);
    fill_k<<<E_ / 256, blk, 0, stream>>>(esrc, edst, et, cursor, elist);

    // --- fused QKV projection: qkv[16384,768] ---
    gemm_bf16<0><<<dim3(6, 128, 1), blk, 0, stream>>>(
        xb, 256, 0, WqkvT, 256, 0, qkv, 768, 0, bq, bk, bv, 256);
    vtrans_k<<<dim3(8, 32, 16), blk, 0, stream>>>(qkv, vtb);

    // --- attention: QK^T, softmax, PV (128-tile) ---
    gemm_bf16<0><<<dim3(8, 8, 16), blk, 0, stream>>>(
        qkv, 768, 786432, qkv + 256, 768, 786432, sP, 1024, 1048576, nullptr, nullptr, nullptr, 256);
    softmax_k<<<BN_, blk, 0, stream>>>(sP);
    gemm_bf16<0><<<dim3(2, 8, 16), blk, 0, stream>>>(
        sP, 1024, 1048576, vtb, 1024, 262144, cat1, 512, 524288, nullptr, nullptr, nullptr, 1024);

    // --- gate (64-tile depth-4), blend+LN ---
    gemm64_bf16<2><<<dim3(4, 256, 1), blk, 0, stream>>>(
        cat1, 512, 0, WgT, 512, 0, gate, 256, 0, bg, 512);
    blend_ln_k<<<BN_ / 4, blk, 0, stream>>>(gate, cat1, xb, valid, lag, lab);

    // --- confidence (64-tile depth-4) + weighted ---
    gemm64_bf16<1><<<dim3(2, 256, 1), blk, 0, stream>>>(
        valid, 256, 0, Wc1T, 256, 0, t1, 128, 0, bc1, 256);
    conf_w_k<<<BN_ / 4, blk, 0, stream>>>(t1, Wc2, bc2, valid, conf, cat2);

    // --- mixer (64-tile depth-4) + LN1 ---
    gemm64_bf16<1><<<dim3(4, 256, 1), blk, 0, stream>>>(
        cat2, 512, 0, WmT, 512, 0, xm, 256, 0, bm, 512);
    ln_k<0><<<BN_ / 4, blk, 0, stream>>>(xm, xn, l1g, l1b);

    // --- RGCN: one GEMM (128-tile, 2304 blocks, XCD-swizzled), gather + LN2 ---
    gemm_bf16<0><<<dim3(18, 128, 1), blk, 0, stream>>>(
        xn, 256, 0, WBIG, 256, 0, hbuf, 2304, 0, nullptr, nullptr, nullptr, 256);
    gather_ln_k<<<BN_ / 4, blk, 0, stream>>>(rowptr, elist, hbuf, cnt8i, brg, l2g, l2b, xr);

    // --- pool + head ---
    pool1_k<<<dim3(B_, 16), blk, 0, stream>>>(xr, conf, part);
    pool2_k<<<B_, blk, 0, stream>>>(part, conf, Wh, bh, outp);
}